// Round 4
// baseline (230.960 us; speedup 1.0000x reference)
//
#include <hip/hip_runtime.h>

// ---- problem constants ----
constexpr int Bc   = 4;
constexpr int Qlen = 2048;
constexpr int Klen = 2048;
constexpr int Dm   = 512;
constexpr int Hh   = 8;
constexpr int HDim = 64;
constexpr float C1 = 0.125f * 1.4426950408889634f;  // attn scale * log2(e), folded into Qp

typedef __attribute__((ext_vector_type(8))) short short8;       // 8x16-bit storage
typedef __attribute__((ext_vector_type(8))) _Float16 half8;     // fp16 MFMA frag
typedef __attribute__((ext_vector_type(2))) __fp16 fp16x2;      // cvt_pkrtz result
typedef __attribute__((ext_vector_type(4))) float f32x4;

__device__ __forceinline__ f32x4 MFMA16(short8 a, short8 b, f32x4 c) {
  return __builtin_amdgcn_mfma_f32_16x16x32_f16(
      __builtin_bit_cast(half8, a), __builtin_bit_cast(half8, b), c, 0, 0, 0);
}

__device__ __forceinline__ void gload_lds16(const void* g, void* l) {
  __builtin_amdgcn_global_load_lds(
      (const __attribute__((address_space(1))) void*)g,
      (__attribute__((address_space(3))) void*)l, 16, 0, 0);
}

__device__ __forceinline__ unsigned short f2h(float f) {
  _Float16 h = (_Float16)f;
  return __builtin_bit_cast(unsigned short, h);
}

__device__ __forceinline__ unsigned pk2h(float a, float b) {
  fp16x2 h = __builtin_amdgcn_cvt_pkrtz(a, b);
  return __builtin_bit_cast(unsigned, h);
}

// ============================================================
// scan_mask: per-batch compaction of unmasked key indices.
// ============================================================
__global__ __launch_bounds__(256) void scan_mask(
    const int* __restrict__ msk, int* __restrict__ idx, int* __restrict__ cnt) {
  const int b = blockIdx.x;
  const int tid = threadIdx.x;
  __shared__ int wtot[4];
  const int* mrow = msk + b * Klen;
  int m8[8];
  int c = 0;
#pragma unroll
  for (int i = 0; i < 8; ++i) {
    m8[i] = mrow[tid * 8 + i];
    c += (m8[i] != 0);
  }
  int pre = c;  // inclusive prefix within wave
#pragma unroll
  for (int off = 1; off < 64; off <<= 1) {
    int t = __shfl_up(pre, off);
    if ((tid & 63) >= off) pre += t;
  }
  const int w = tid >> 6;
  if ((tid & 63) == 63) wtot[w] = pre;
  __syncthreads();
  int base = 0;
  for (int i = 0; i < w; ++i) base += wtot[i];
  int p = base + pre - c;  // exclusive prefix for this thread
#pragma unroll
  for (int i = 0; i < 8; ++i)
    if (m8[i] != 0) idx[b * Klen + (p++)] = tid * 8 + i;
  if (tid == 255) cnt[b] = base + pre;
}

// ============================================================
// cvt4: f32->fp16 of the 4 weight matrices (+ mask bias, fallback path)
// ============================================================
__global__ __launch_bounds__(256) void cvt4(
    const float* __restrict__ s0, const float* __restrict__ s1,
    const float* __restrict__ s2, const float* __restrict__ s3,
    unsigned short* __restrict__ o0, unsigned short* __restrict__ o1,
    unsigned short* __restrict__ o2, unsigned short* __restrict__ o3,
    const int* __restrict__ msk, float* __restrict__ biasf) {
  const int seg = blockIdx.y;
  int i = (blockIdx.x * 256 + threadIdx.x) * 4;
  if (seg < 4) {
    const float* s = (seg == 0) ? s0 : (seg == 1) ? s1 : (seg == 2) ? s2 : s3;
    unsigned short* o = (seg == 0) ? o0 : (seg == 1) ? o1 : (seg == 2) ? o2 : o3;
    float4 x = *(const float4*)(s + i);
    unsigned t[2] = {pk2h(x.x, x.y), pk2h(x.z, x.w)};
    *(uint2*)(o + i) = *(const uint2*)t;
  } else if (i + 3 < Bc * Klen) {
    int4 m = *(const int4*)(msk + i);
    float4 bo;
    bo.x = (m.x == 0) ? -60000.0f : 0.0f;
    bo.y = (m.y == 0) ? -60000.0f : 0.0f;
    bo.z = (m.z == 0) ? -60000.0f : 0.0f;
    bo.w = (m.w == 0) ? -60000.0f : 0.0f;
    *(float4*)(biasf + i) = bo;
  }
}

// ============================================================
// cvt_in: f32->fp16. seg 0 = Q copy; segs 1,2 = K,V row-gather.
// ============================================================
__global__ __launch_bounds__(256) void cvt_in(
    const float* __restrict__ q, const float* __restrict__ k,
    const float* __restrict__ v,
    unsigned short* __restrict__ qh, unsigned short* __restrict__ kh,
    unsigned short* __restrict__ vh,
    const int* __restrict__ idx, const int* __restrict__ cnt) {
  const int seg = blockIdx.y;
  int g = blockIdx.x * 256 + threadIdx.x;
  int i = g * 4;
  if (seg == 0) {
    float4 x = *(const float4*)(q + i);
    unsigned t[2] = {pk2h(x.x, x.y), pk2h(x.z, x.w)};
    *(uint2*)(qh + i) = *(const uint2*)t;
    return;
  }
  const float* s = (seg == 1) ? k : v;
  unsigned short* o = (seg == 1) ? kh : vh;
  int row = i >> 9, col = i & 511;
  int b = row >> 11, jc = row & 2047;
  int cb = cnt[b];
  if (jc < cb) {
    int j = idx[b * Klen + jc];
    float4 x = *(const float4*)(s + ((size_t)(b * Klen + j)) * 512 + col);
    unsigned t[2] = {pk2h(x.x, x.y), pk2h(x.z, x.w)};
    *(uint2*)(o + (size_t)row * 512 + col) = *(const uint2*)t;
  } else if (jc < ((cb + 127) & ~127)) {
    uint2 z = {0u, 0u};
    *(uint2*)(o + (size_t)row * 512 + col) = z;
  }
}

// ============================================================
// Fused QKV projection, double-buffered staging (1 barrier/iter).
// Q output pre-scaled by C1.
// ============================================================
template <bool F16A>
__global__ __launch_bounds__(256) void gemm_qkv(
    const float* __restrict__ q_in,
    const float* __restrict__ k_in,
    const float* __restrict__ v_in,
    const unsigned short* __restrict__ qh,
    const unsigned short* __restrict__ kh,
    const unsigned short* __restrict__ vh,
    const unsigned short* __restrict__ Wqh,
    const unsigned short* __restrict__ Wkh,
    const unsigned short* __restrict__ Wvh,
    unsigned short* __restrict__ Qp,
    unsigned short* __restrict__ Kp,
    unsigned short* __restrict__ Vp,
    const int* __restrict__ cnt) {
  __shared__ unsigned short As[2][128 * 32];
  __shared__ unsigned short Bs[2][128 * 32];
  const int tid = threadIdx.x;
  const int w = tid >> 6, l = tid & 63;
  const int quad = l >> 4, l15 = l & 15;
  const int m0 = blockIdx.x * 128;
  const int n0 = blockIdx.y * 128;
  const int seg = n0 >> 9;
  const int f0  = n0 & 511;
  if constexpr (F16A) {
    if (seg != 0) {
      int local = m0 & 2047;
      if (local >= ((cnt[m0 >> 11] + 63) & ~63)) return;
    }
  }
  const float* Af = (seg == 0) ? q_in : (seg == 1) ? k_in : v_in;
  const unsigned short* Ah = (seg == 0) ? qh : (seg == 1) ? kh : vh;
  const unsigned short* W = (seg == 0) ? Wqh : (seg == 1) ? Wkh : Wvh;
  unsigned short* dst = (seg == 0) ? Qp : (seg == 1) ? Kp : Vp;

  f32x4 acc[4][4] = {};
  const int lrow = l >> 2;
  const int lcol = (l & 3) * 8;
  const int wm = (w >> 1) * 64, wn = (w & 1) * 64;

  auto stage = [&](int bs, int kk) {
#pragma unroll
    for (int i = 0; i < 2; ++i) {
      int row = w * 32 + i * 16 + lrow;
      if constexpr (F16A) {
        gload_lds16(Ah + (size_t)(m0 + row) * 512 + kk + lcol, &As[bs][row * 32 + lcol]);
      } else {
        const float* ap = Af + (size_t)(m0 + row) * 512 + kk + lcol;
        float4 x0 = *(const float4*)(ap);
        float4 x1 = *(const float4*)(ap + 4);
        unsigned t[4] = {pk2h(x0.x, x0.y), pk2h(x0.z, x0.w),
                         pk2h(x1.x, x1.y), pk2h(x1.z, x1.w)};
        *(uint4*)&As[bs][row * 32 + lcol] = *(const uint4*)t;
      }
      gload_lds16(W + (size_t)(f0 + row) * 512 + kk + lcol, &Bs[bs][row * 32 + lcol]);
    }
  };

  stage(0, 0);
  for (int kk = 0; kk < 512; kk += 32) {
    const int cur = (kk >> 5) & 1;
    __syncthreads();                 // drains vmcnt: stage(cur) complete
    if (kk + 32 < 512) stage(cur ^ 1, kk + 32);  // prefetch next, hidden under MFMA
    short8 af[4], bf[4];
#pragma unroll
    for (int t = 0; t < 4; ++t)
      af[t] = *(const short8*)&As[cur][(wm + t * 16 + l15) * 32 + quad * 8];
#pragma unroll
    for (int t = 0; t < 4; ++t)
      bf[t] = *(const short8*)&Bs[cur][(wn + t * 16 + l15) * 32 + quad * 8];
#pragma unroll
    for (int mt = 0; mt < 4; ++mt)
#pragma unroll
      for (int nt = 0; nt < 4; ++nt)
        acc[mt][nt] = MFMA16(af[mt], bf[nt], acc[mt][nt]);
  }
  const float oscale = (seg == 0) ? C1 : 1.0f;
#pragma unroll
  for (int mt = 0; mt < 4; ++mt)
#pragma unroll
    for (int nt = 0; nt < 4; ++nt)
#pragma unroll
      for (int r = 0; r < 4; ++r) {
        int m  = m0 + wm + mt * 16 + quad * 4 + r;
        int nn = f0 + wn + nt * 16 + l15;
        int b = m >> 11, qq = m & 2047;
        int h = nn >> 6, hd = nn & 63;
        dst[(((size_t)(b * Hh + h)) * Qlen + qq) * HDim + hd] =
            f2h(acc[mt][nt][r] * oscale);
      }
}

// ============================================================
// V transpose (cnt != nullptr: skip tiles beyond padded key count)
// ============================================================
__global__ __launch_bounds__(256) void transpose_v(
    const unsigned short* __restrict__ Vp, unsigned short* __restrict__ Vt,
    const int* __restrict__ cnt) {
  __shared__ unsigned short t[64 * 72];
  const int bh = blockIdx.y, jt = blockIdx.x;
  if (cnt) {
    if (jt * 64 >= ((cnt[bh >> 3] + 63) & ~63)) return;
  }
  const int tid = threadIdx.x;
#pragma unroll
  for (int i = 0; i < 2; ++i) {
    int g = i * 256 + tid;
    int j = g >> 3, c8 = g & 7;
    *(uint4*)&t[j * 72 + c8 * 8] =
        *(const uint4*)(Vp + ((size_t)bh * Klen + jt * 64 + j) * 64 + c8 * 8);
  }
  __syncthreads();
#pragma unroll
  for (int i = 0; i < 2; ++i) {
    int g = i * 256 + tid;
    int d = g >> 3, j8 = g & 7;
    unsigned short tmp[8];
#pragma unroll
    for (int kx = 0; kx < 8; ++kx) tmp[kx] = t[(j8 * 8 + kx) * 72 + d];
    *(uint4*)(Vt + ((size_t)bh * HDim + d) * Klen + jt * 64 + j8 * 8) = *(const uint4*)tmp;
  }
}

// ============================================================
// Output projection, double-buffered staging (1 barrier/iter)
// ============================================================
__global__ __launch_bounds__(256) void gemm_out(
    const unsigned short* __restrict__ Oa,
    const unsigned short* __restrict__ Woh,
    float* __restrict__ out) {
  __shared__ unsigned short As[2][128 * 32];
  __shared__ unsigned short Bs[2][128 * 32];
  const int tid = threadIdx.x;
  const int w = tid >> 6, l = tid & 63;
  const int quad = l >> 4, l15 = l & 15;
  const int m0 = blockIdx.x * 128;
  const int n0 = blockIdx.y * 128;

  f32x4 acc[4][4] = {};
  const int lrow = l >> 2;
  const int lcol = (l & 3) * 8;
  const int wm = (w >> 1) * 64, wn = (w & 1) * 64;

  auto stage = [&](int bs, int kk) {
#pragma unroll
    for (int i = 0; i < 2; ++i) {
      int row = w * 32 + i * 16 + lrow;
      gload_lds16(Oa + (size_t)(m0 + row) * 512 + kk + lcol, &As[bs][row * 32 + lcol]);
      gload_lds16(Woh + (size_t)(n0 + row) * 512 + kk + lcol, &Bs[bs][row * 32 + lcol]);
    }
  };

  stage(0, 0);
  for (int kk = 0; kk < 512; kk += 32) {
    const int cur = (kk >> 5) & 1;
    __syncthreads();
    if (kk + 32 < 512) stage(cur ^ 1, kk + 32);
    short8 af[4], bf[4];
#pragma unroll
    for (int t = 0; t < 4; ++t)
      af[t] = *(const short8*)&As[cur][(wm + t * 16 + l15) * 32 + quad * 8];
#pragma unroll
    for (int t = 0; t < 4; ++t)
      bf[t] = *(const short8*)&Bs[cur][(wn + t * 16 + l15) * 32 + quad * 8];
#pragma unroll
    for (int mt = 0; mt < 4; ++mt)
#pragma unroll
      for (int nt = 0; nt < 4; ++nt)
        acc[mt][nt] = MFMA16(af[mt], bf[nt], acc[mt][nt]);
  }
#pragma unroll
  for (int mt = 0; mt < 4; ++mt)
#pragma unroll
    for (int nt = 0; nt < 4; ++nt)
#pragma unroll
      for (int r = 0; r < 4; ++r) {
        int m  = m0 + wm + mt * 16 + quad * 4 + r;
        int nn = n0 + wn + nt * 16 + l15;
        out[(size_t)m * 512 + nn] = acc[mt][nt][r];
      }
}

// ============================================================
// Flash attention. Single-buffered K staging (occupancy > explicit
// dbuf, per R3 regression); V is NOT staged: same-bh blocks pin to
// one XCD so Vt is L2-resident — PV A-fragments load straight from
// global into registers (clean 16B loads, drained by the same
// barrier as K staging). LDS = Ks + Ps only (17.2 KB).
// ============================================================
template <bool KSPLIT, bool COMPACT>
__global__ __launch_bounds__(256, 4) void attn(
    const unsigned short* __restrict__ Qp,
    const unsigned short* __restrict__ Kp,
    const unsigned short* __restrict__ Vt,
    const float* __restrict__ biasf,
    const int* __restrict__ cntArr,
    unsigned short* __restrict__ Oa,     // SINGLE: (B,Q,D) out
    unsigned short* __restrict__ Op,     // KSPLIT: partial O [part][bh][qrow][64]
    float* __restrict__ Sp) {            // KSPLIT: logsumexp [part][bh*Qlen]
  __shared__ unsigned short Ks[64 * 64];
  __shared__ unsigned short Ps[4][16 * 72];

  const int tid = threadIdx.x;
  const int w = tid >> 6, l = tid & 63;
  const int quad = l >> 4, l15 = l & 15;
  const int bid = blockIdx.x;
  const int bh = bid & 31;            // same bh -> same XCD
  const int b = bh >> 3, h = bh & 7;

  int cnt, KT;
  if constexpr (COMPACT) {
    cnt = cntArr[b];
    KT = (cnt + 63) >> 6;
  } else {
    cnt = Klen;
    KT = Klen / 64;
  }

  int qt, part, kt0, ktN;
  if constexpr (KSPLIT) {
    int rest = bid >> 5;              // 0..63
    part = rest & 1;
    qt = rest >> 1;
    int half = (KT + 1) >> 1;
    kt0 = part ? half : 0;
    ktN = part ? KT : half;
  } else {
    part = 0; qt = bid >> 5; kt0 = 0; ktN = KT;
  }
  const int x = l15 & 7;
  const int qrow = qt * 64 + w * 16 + l15;

  short8 aq[2];
#pragma unroll
  for (int k2 = 0; k2 < 2; ++k2)
    aq[k2] = *(const short8*)(Qp + ((size_t)bh * Qlen + qrow) * HDim + (k2 * 4 + quad) * 8);

  short8 ones;
#pragma unroll
  for (int j = 0; j < 8; ++j) ones[j] = (short)0x3C00;  // fp16 1.0

  f32x4 o[4] = {};
  f32x4 o5 = {};                       // row-sum accumulator (l), via MFMA
  float m_run = -1.0e6f;
  const float* brow = biasf + b * Klen;  // only used when !COMPACT
  // per-lane V base: row d = ctd*16 + l15, keys from kt*64 + quad*8
  const unsigned short* vbase =
      Vt + ((size_t)bh * HDim + l15) * Klen + quad * 8;

  for (int kt = kt0; kt < ktN; ++kt) {
    __syncthreads();                       // all waves done reading Ks[prev]
    // V fragments for this tile: global -> regs (L2-resident)
    short8 vb0[4], vb1[4];
#pragma unroll
    for (int ctd = 0; ctd < 4; ++ctd) {
      const unsigned short* p = vbase + (size_t)(ctd * 16) * Klen + kt * 64;
      vb0[ctd] = *(const short8*)p;
      vb1[ctd] = *(const short8*)(p + 32);
    }
    // K tile: global -> LDS (swizzled source, linear dest)
#pragma unroll
    for (int i = 0; i < 2; ++i) {
      int g = i * 256 + tid;
      int row = g >> 3, c8 = g & 7;
      int sb = (c8 ^ (row & 7)) * 8;
      gload_lds16(Kp + ((size_t)bh * Klen + kt * 64 + row) * HDim + sb, &Ks[g * 8]);
    }
    float4 bb[4];
    if constexpr (!COMPACT) {
#pragma unroll
      for (int ct = 0; ct < 4; ++ct)
        bb[ct] = *(const float4*)(brow + kt * 64 + ct * 16 + quad * 4);
    }
    __syncthreads();                       // drains vmcnt: Ks + V regs ready

    // ---- S^T = K . Q^T (Q pre-scaled by C1 -> exp2 domain) ----
    f32x4 sv[4];
    __builtin_amdgcn_s_setprio(1);
#pragma unroll
    for (int ct = 0; ct < 4; ++ct) {
      const short8 bk0 = *(const short8*)&Ks[(ct * 16 + l15) * 64 + (quad ^ x) * 8];
      const short8 bk1 = *(const short8*)&Ks[(ct * 16 + l15) * 64 + ((4 + quad) ^ x) * 8];
      f32x4 a = {};
      a = MFMA16(bk0, aq[0], a);
      a = MFMA16(bk1, aq[1], a);
      sv[ct] = a;
    }
    __builtin_amdgcn_s_setprio(0);

    if constexpr (!COMPACT) {
#pragma unroll
      for (int ct = 0; ct < 4; ++ct)
#pragma unroll
        for (int r = 0; r < 4; ++r)
          sv[ct][r] += bb[ct][r];
    } else {
      if (kt == KT - 1) {  // mask the pad keys in the final tile
#pragma unroll
        for (int ct = 0; ct < 4; ++ct)
#pragma unroll
          for (int r = 0; r < 4; ++r)
            if (kt * 64 + ct * 16 + quad * 4 + r >= cnt) sv[ct][r] = -60000.0f;
      }
    }

    // ---- per-q max (cross-quad) + deferred rescale ----
    float mx0 = fmaxf(fmaxf(sv[0][0], sv[0][1]), fmaxf(sv[0][2], sv[0][3]));
    float mx1 = fmaxf(fmaxf(sv[1][0], sv[1][1]), fmaxf(sv[1][2], sv[1][3]));
    float mx2 = fmaxf(fmaxf(sv[2][0], sv[2][1]), fmaxf(sv[2][2], sv[2][3]));
    float mx3 = fmaxf(fmaxf(sv[3][0], sv[3][1]), fmaxf(sv[3][2], sv[3][3]));
    float mx = fmaxf(fmaxf(mx0, mx1), fmaxf(mx2, mx3));
    mx = fmaxf(mx, __shfl_xor(mx, 16));
    mx = fmaxf(mx, __shfl_xor(mx, 32));
    if (__any(mx > m_run + 8.0f)) {
      float mnew  = fmaxf(m_run, mx);
      float alpha = exp2f(m_run - mnew);
      m_run = mnew;
#pragma unroll
      for (int ctd = 0; ctd < 4; ++ctd) o[ctd] *= alpha;
      o5 *= alpha;
    }

    // ---- P = exp2(S - m), pack to wave-private Ps ----
#pragma unroll
    for (int ct = 0; ct < 4; ++ct) {
      float p0 = exp2f(sv[ct][0] - m_run);
      float p1 = exp2f(sv[ct][1] - m_run);
      float p2 = exp2f(sv[ct][2] - m_run);
      float p3 = exp2f(sv[ct][3] - m_run);
      unsigned pk[2] = {pk2h(p0, p1), pk2h(p2, p3)};
      *(uint2*)&Ps[w][l15 * 72 + ct * 16 + quad * 4] = *(const uint2*)pk;
    }
    const short8 ap0 = *(const short8*)&Ps[w][l15 * 72 + quad * 8];
    const short8 ap1 = *(const short8*)&Ps[w][l15 * 72 + 32 + quad * 8];

    // ---- l += ones . P^T ; O^T += V^T . P^T (V from regs) ----
    __builtin_amdgcn_s_setprio(1);
    o5 = MFMA16(ones, ap0, o5);
    o5 = MFMA16(ones, ap1, o5);
#pragma unroll
    for (int ctd = 0; ctd < 4; ++ctd) {
      o[ctd] = MFMA16(vb0[ctd], ap0, o[ctd]);
      o[ctd] = MFMA16(vb1[ctd], ap1, o[ctd]);
    }
    __builtin_amdgcn_s_setprio(0);
  }

  // ---- epilogue: l is replicated in every element of o5 ----
  float lt = o5[0];
  float rl = (lt > 0.0f) ? 1.0f / lt : 0.0f;
  if constexpr (KSPLIT) {
    const size_t pbase = ((size_t)part * 32 + bh) * Qlen;  // rows of this part
    const size_t obase = (pbase + qrow) * 64;
#pragma unroll
    for (int ctd = 0; ctd < 4; ++ctd) {
      unsigned pk[2] = {pk2h(o[ctd][0] * rl, o[ctd][1] * rl),
                        pk2h(o[ctd][2] * rl, o[ctd][3] * rl)};
      *(uint2*)(Op + obase + ctd * 16 + quad * 4) = *(const uint2*)pk;
    }
    if (l < 16)  // one lane per q-row (quad==0)
      Sp[pbase + qrow] = (lt > 0.0f) ? m_run + log2f(lt) : -1.0e30f;
  } else {
    const size_t obase = ((size_t)(b * Qlen) + qrow) * Dm + h * 64;
#pragma unroll
    for (int ctd = 0; ctd < 4; ++ctd) {
      unsigned pk[2] = {pk2h(o[ctd][0] * rl, o[ctd][1] * rl),
                        pk2h(o[ctd][2] * rl, o[ctd][3] * rl)};
      *(uint2*)(Oa + obase + ctd * 16 + quad * 4) = *(const uint2*)pk;
    }
  }
}

// ============================================================
// reduce_o: combine the 2 K-split partials -> Oa (B,Q,D) fp16
// ============================================================
__global__ __launch_bounds__(256) void reduce_o(
    const unsigned short* __restrict__ Op, const float* __restrict__ Sp,
    unsigned short* __restrict__ Oa) {
  int g = blockIdx.x * 256 + threadIdx.x;
  int row = g >> 3, c8 = g & 7;              // row = bh*Qlen + qrow
  const size_t PART = (size_t)32 * Qlen;     // rows per part
  float s1 = Sp[row], s2 = Sp[PART + row];
  float M = fmaxf(s1, s2);
  float w1 = exp2f(s1 - M), w2 = exp2f(s2 - M);
  float rs = 1.0f / (w1 + w2);
  w1 *= rs; w2 *= rs;
  short8 a = *(const short8*)(Op + (size_t)row * 64 + c8 * 8);
  short8 bvec = *(const short8*)(Op + (PART + row) * 64 + c8 * 8);
  half8 af = __builtin_bit_cast(half8, a);
  half8 bf = __builtin_bit_cast(half8, bvec);
  unsigned pk[4];
#pragma unroll
  for (int i = 0; i < 4; ++i) {
    float r0 = w1 * (float)af[i * 2 + 0] + w2 * (float)bf[i * 2 + 0];
    float r1 = w1 * (float)af[i * 2 + 1] + w2 * (float)bf[i * 2 + 1];
    pk[i] = pk2h(r0, r1);
  }
  int bh = row >> 11, qrow = row & 2047;
  int b = bh >> 3, h = bh & 7;
  *(uint4*)(Oa + ((size_t)(b * Qlen) + qrow) * Dm + h * 64 + c8 * 8) =
      *(const uint4*)pk;
}

extern "C" void kernel_launch(void* const* d_in, const int* in_sizes, int n_in,
                              void* d_out, int out_size, void* d_ws, size_t ws_size,
                              hipStream_t stream) {
  const float* q  = (const float*)d_in[0];
  const float* k  = (const float*)d_in[1];
  const float* v  = (const float*)d_in[2];
  const float* Wq = (const float*)d_in[3];
  const float* Wk = (const float*)d_in[4];
  const float* Wv = (const float*)d_in[5];
  const float* Wo = (const float*)d_in[6];
  const int*  msk = (const int*)d_in[7];
  float* out = (float*)d_out;

  char* ws = (char*)d_ws;
  const size_t SEG  = (size_t)Bc * Hh * Qlen * HDim * sizeof(unsigned short); // 8 MB
  const size_t WSEG = (size_t)Dm * Dm * sizeof(unsigned short);               // 0.5 MB
  unsigned short* Qp  = (unsigned short*)(ws);
  unsigned short* Kp  = (unsigned short*)(ws + SEG);
  unsigned short* Vp  = (unsigned short*)(ws + 2 * SEG);
  unsigned short* Vt  = (unsigned short*)(ws + 3 * SEG);
  unsigned short* Oa  = Vp;  // Vp dead after transpose_v
  unsigned short* Wqh = (unsigned short*)(ws + 4 * SEG);
  unsigned short* Wkh = (unsigned short*)(ws + 4 * SEG + WSEG);
  unsigned short* Wvh = (unsigned short*)(ws + 4 * SEG + 2 * WSEG);
  unsigned short* Woh = (unsigned short*)(ws + 4 * SEG + 3 * WSEG);
  // 64 KB region: big path = idx (32 KB) + cnt; small path = f32 bias (32 KB)
  int*   idxArr = (int*)(ws + 4 * SEG + 4 * WSEG);
  int*   cntArr = idxArr + Bc * Klen;
  float* Bfs    = (float*)idxArr;
  unsigned short* qh  = (unsigned short*)(ws + 4 * SEG + 4 * WSEG + 65536);
  unsigned short* kh  = qh + SEG / 2;
  unsigned short* vh  = kh + SEG / 2;
  // K-split partials alias qh/kh (dead after gemm_qkv); Sp aliases vh.
  unsigned short* Op  = qh;                  // 2 parts x 8 MB
  float*          Sp  = (float*)vh;          // 2 x 64K floats = 512 KB
  const size_t NEED = 4 * SEG + 4 * WSEG + 65536 + 3 * SEG;
  const bool big = ws_size >= NEED;

  // bind multi-arg template instantiations outside the launch macro
  auto attn_split  = attn<true, true>;
  auto attn_single = attn<false, false>;

  const int wn = Dm * Dm;
  if (big) {
    hipLaunchKernelGGL(scan_mask, dim3(Bc), dim3(256), 0, stream, msk, idxArr, cntArr);
    hipLaunchKernelGGL(cvt4, dim3(wn / 1024, 4), dim3(256), 0, stream,
                       Wq, Wk, Wv, Wo, Wqh, Wkh, Wvh, Woh, msk, Bfs);
    hipLaunchKernelGGL(cvt_in, dim3(4096, 3), dim3(256), 0, stream,
                       q, k, v, qh, kh, vh, idxArr, cntArr);
    hipLaunchKernelGGL(gemm_qkv<true>, dim3(64, 12), dim3(256), 0, stream,
                       q, k, v, qh, kh, vh, Wqh, Wkh, Wvh, Qp, Kp, Vp, cntArr);
    hipLaunchKernelGGL(transpose_v, dim3(32, 32), dim3(256), 0, stream, Vp, Vt, cntArr);
    hipLaunchKernelGGL(attn_split, dim3(2048), dim3(256), 0, stream,
                       Qp, Kp, Vt, Bfs, cntArr, Oa, Op, Sp);
    hipLaunchKernelGGL(reduce_o, dim3(2048), dim3(256), 0, stream, Op, Sp, Oa);
  } else {
    hipLaunchKernelGGL(cvt4, dim3(wn / 1024, 5), dim3(256), 0, stream,
                       Wq, Wk, Wv, Wo, Wqh, Wkh, Wvh, Woh, msk, Bfs);
    hipLaunchKernelGGL(gemm_qkv<false>, dim3(64, 12), dim3(256), 0, stream,
                       q, k, v, qh, kh, vh, Wqh, Wkh, Wvh, Qp, Kp, Vp, cntArr);
    hipLaunchKernelGGL(transpose_v, dim3(32, 32), dim3(256), 0, stream, Vp, Vt,
                       (const int*)nullptr);
    hipLaunchKernelGGL(attn_single, dim3(1024), dim3(256), 0, stream,
                       Qp, Kp, Vt, Bfs, (const int*)nullptr, Oa, Op, Sp);
  }
  hipLaunchKernelGGL(gemm_out, dim3(64, 4), dim3(256), 0, stream, Oa, Woh, out);
}

// Round 6
// 189.867 us; speedup vs baseline: 1.2164x; 1.2164x over previous
//
#include <hip/hip_runtime.h>

// ---- problem constants ----
constexpr int Bc   = 4;
constexpr int Qlen = 2048;
constexpr int Klen = 2048;
constexpr int Dm   = 512;
constexpr int Hh   = 8;
constexpr int HDim = 64;
constexpr float C1 = 0.125f * 1.4426950408889634f;  // attn scale * log2(e), folded into Qp

typedef __attribute__((ext_vector_type(8))) short short8;       // 8x16-bit storage
typedef __attribute__((ext_vector_type(8))) _Float16 half8;     // fp16 MFMA frag
typedef __attribute__((ext_vector_type(2))) __fp16 fp16x2;      // cvt_pkrtz result
typedef __attribute__((ext_vector_type(4))) float f32x4;

__device__ __forceinline__ f32x4 MFMA16(short8 a, short8 b, f32x4 c) {
  return __builtin_amdgcn_mfma_f32_16x16x32_f16(
      __builtin_bit_cast(half8, a), __builtin_bit_cast(half8, b), c, 0, 0, 0);
}

__device__ __forceinline__ void gload_lds16(const void* g, void* l) {
  __builtin_amdgcn_global_load_lds(
      (const __attribute__((address_space(1))) void*)g,
      (__attribute__((address_space(3))) void*)l, 16, 0, 0);
}

__device__ __forceinline__ unsigned short f2h(float f) {
  _Float16 h = (_Float16)f;
  return __builtin_bit_cast(unsigned short, h);
}

__device__ __forceinline__ unsigned pk2h(float a, float b) {
  fp16x2 h = __builtin_amdgcn_cvt_pkrtz(a, b);
  return __builtin_bit_cast(unsigned, h);
}

// ============================================================
// scan_mask: per-batch compaction of unmasked key indices.
// ============================================================
__global__ __launch_bounds__(256) void scan_mask(
    const int* __restrict__ msk, int* __restrict__ idx, int* __restrict__ cnt) {
  const int b = blockIdx.x;
  const int tid = threadIdx.x;
  __shared__ int wtot[4];
  const int* mrow = msk + b * Klen;
  int m8[8];
  int c = 0;
#pragma unroll
  for (int i = 0; i < 8; ++i) {
    m8[i] = mrow[tid * 8 + i];
    c += (m8[i] != 0);
  }
  int pre = c;  // inclusive prefix within wave
#pragma unroll
  for (int off = 1; off < 64; off <<= 1) {
    int t = __shfl_up(pre, off);
    if ((tid & 63) >= off) pre += t;
  }
  const int w = tid >> 6;
  if ((tid & 63) == 63) wtot[w] = pre;
  __syncthreads();
  int base = 0;
  for (int i = 0; i < w; ++i) base += wtot[i];
  int p = base + pre - c;  // exclusive prefix for this thread
#pragma unroll
  for (int i = 0; i < 8; ++i)
    if (m8[i] != 0) idx[b * Klen + (p++)] = tid * 8 + i;
  if (tid == 255) cnt[b] = base + pre;
}

// ============================================================
// cvt4: f32->fp16 of the 4 weight matrices (+ mask bias, fallback path)
// ============================================================
__global__ __launch_bounds__(256) void cvt4(
    const float* __restrict__ s0, const float* __restrict__ s1,
    const float* __restrict__ s2, const float* __restrict__ s3,
    unsigned short* __restrict__ o0, unsigned short* __restrict__ o1,
    unsigned short* __restrict__ o2, unsigned short* __restrict__ o3,
    const int* __restrict__ msk, float* __restrict__ biasf) {
  const int seg = blockIdx.y;
  int i = (blockIdx.x * 256 + threadIdx.x) * 4;
  if (seg < 4) {
    const float* s = (seg == 0) ? s0 : (seg == 1) ? s1 : (seg == 2) ? s2 : s3;
    unsigned short* o = (seg == 0) ? o0 : (seg == 1) ? o1 : (seg == 2) ? o2 : o3;
    float4 x = *(const float4*)(s + i);
    unsigned t[2] = {pk2h(x.x, x.y), pk2h(x.z, x.w)};
    *(uint2*)(o + i) = *(const uint2*)t;
  } else if (i + 3 < Bc * Klen) {
    int4 m = *(const int4*)(msk + i);
    float4 bo;
    bo.x = (m.x == 0) ? -60000.0f : 0.0f;
    bo.y = (m.y == 0) ? -60000.0f : 0.0f;
    bo.z = (m.z == 0) ? -60000.0f : 0.0f;
    bo.w = (m.w == 0) ? -60000.0f : 0.0f;
    *(float4*)(biasf + i) = bo;
  }
}

// ============================================================
// cvt_in: f32->fp16. seg 0 = Q copy; segs 1,2 = K,V row-gather.
// ============================================================
__global__ __launch_bounds__(256) void cvt_in(
    const float* __restrict__ q, const float* __restrict__ k,
    const float* __restrict__ v,
    unsigned short* __restrict__ qh, unsigned short* __restrict__ kh,
    unsigned short* __restrict__ vh,
    const int* __restrict__ idx, const int* __restrict__ cnt) {
  const int seg = blockIdx.y;
  int g = blockIdx.x * 256 + threadIdx.x;
  int i = g * 4;
  if (seg == 0) {
    float4 x = *(const float4*)(q + i);
    unsigned t[2] = {pk2h(x.x, x.y), pk2h(x.z, x.w)};
    *(uint2*)(qh + i) = *(const uint2*)t;
    return;
  }
  const float* s = (seg == 1) ? k : v;
  unsigned short* o = (seg == 1) ? kh : vh;
  int row = i >> 9, col = i & 511;
  int b = row >> 11, jc = row & 2047;
  int cb = cnt[b];
  if (jc < cb) {
    int j = idx[b * Klen + jc];
    float4 x = *(const float4*)(s + ((size_t)(b * Klen + j)) * 512 + col);
    unsigned t[2] = {pk2h(x.x, x.y), pk2h(x.z, x.w)};
    *(uint2*)(o + (size_t)row * 512 + col) = *(const uint2*)t;
  } else if (jc < ((cb + 127) & ~127)) {
    uint2 z = {0u, 0u};
    *(uint2*)(o + (size_t)row * 512 + col) = z;
  }
}

// ============================================================
// Fused QKV projection, double-buffered staging (1 barrier/iter).
// Q output pre-scaled by C1.
// ============================================================
template <bool F16A>
__global__ __launch_bounds__(256) void gemm_qkv(
    const float* __restrict__ q_in,
    const float* __restrict__ k_in,
    const float* __restrict__ v_in,
    const unsigned short* __restrict__ qh,
    const unsigned short* __restrict__ kh,
    const unsigned short* __restrict__ vh,
    const unsigned short* __restrict__ Wqh,
    const unsigned short* __restrict__ Wkh,
    const unsigned short* __restrict__ Wvh,
    unsigned short* __restrict__ Qp,
    unsigned short* __restrict__ Kp,
    unsigned short* __restrict__ Vp,
    const int* __restrict__ cnt) {
  __shared__ unsigned short As[2][128 * 32];
  __shared__ unsigned short Bs[2][128 * 32];
  const int tid = threadIdx.x;
  const int w = tid >> 6, l = tid & 63;
  const int quad = l >> 4, l15 = l & 15;
  const int m0 = blockIdx.x * 128;
  const int n0 = blockIdx.y * 128;
  const int seg = n0 >> 9;
  const int f0  = n0 & 511;
  if constexpr (F16A) {
    if (seg != 0) {
      int local = m0 & 2047;
      if (local >= ((cnt[m0 >> 11] + 63) & ~63)) return;
    }
  }
  const float* Af = (seg == 0) ? q_in : (seg == 1) ? k_in : v_in;
  const unsigned short* Ah = (seg == 0) ? qh : (seg == 1) ? kh : vh;
  const unsigned short* W = (seg == 0) ? Wqh : (seg == 1) ? Wkh : Wvh;
  unsigned short* dst = (seg == 0) ? Qp : (seg == 1) ? Kp : Vp;

  f32x4 acc[4][4] = {};
  const int lrow = l >> 2;
  const int lcol = (l & 3) * 8;
  const int wm = (w >> 1) * 64, wn = (w & 1) * 64;

  auto stage = [&](int bs, int kk) {
#pragma unroll
    for (int i = 0; i < 2; ++i) {
      int row = w * 32 + i * 16 + lrow;
      if constexpr (F16A) {
        gload_lds16(Ah + (size_t)(m0 + row) * 512 + kk + lcol, &As[bs][row * 32 + lcol]);
      } else {
        const float* ap = Af + (size_t)(m0 + row) * 512 + kk + lcol;
        float4 x0 = *(const float4*)(ap);
        float4 x1 = *(const float4*)(ap + 4);
        unsigned t[4] = {pk2h(x0.x, x0.y), pk2h(x0.z, x0.w),
                         pk2h(x1.x, x1.y), pk2h(x1.z, x1.w)};
        *(uint4*)&As[bs][row * 32 + lcol] = *(const uint4*)t;
      }
      gload_lds16(W + (size_t)(f0 + row) * 512 + kk + lcol, &Bs[bs][row * 32 + lcol]);
    }
  };

  stage(0, 0);
  for (int kk = 0; kk < 512; kk += 32) {
    const int cur = (kk >> 5) & 1;
    __syncthreads();                 // drains vmcnt: stage(cur) complete
    if (kk + 32 < 512) stage(cur ^ 1, kk + 32);  // prefetch next, hidden under MFMA
    short8 af[4], bf[4];
#pragma unroll
    for (int t = 0; t < 4; ++t)
      af[t] = *(const short8*)&As[cur][(wm + t * 16 + l15) * 32 + quad * 8];
#pragma unroll
    for (int t = 0; t < 4; ++t)
      bf[t] = *(const short8*)&Bs[cur][(wn + t * 16 + l15) * 32 + quad * 8];
#pragma unroll
    for (int mt = 0; mt < 4; ++mt)
#pragma unroll
      for (int nt = 0; nt < 4; ++nt)
        acc[mt][nt] = MFMA16(af[mt], bf[nt], acc[mt][nt]);
  }
  const float oscale = (seg == 0) ? C1 : 1.0f;
#pragma unroll
  for (int mt = 0; mt < 4; ++mt)
#pragma unroll
    for (int nt = 0; nt < 4; ++nt)
#pragma unroll
      for (int r = 0; r < 4; ++r) {
        int m  = m0 + wm + mt * 16 + quad * 4 + r;
        int nn = f0 + wn + nt * 16 + l15;
        int b = m >> 11, qq = m & 2047;
        int h = nn >> 6, hd = nn & 63;
        dst[(((size_t)(b * Hh + h)) * Qlen + qq) * HDim + hd] =
            f2h(acc[mt][nt][r] * oscale);
      }
}

// ============================================================
// V transpose (cnt != nullptr: skip tiles beyond padded key count)
// ============================================================
__global__ __launch_bounds__(256) void transpose_v(
    const unsigned short* __restrict__ Vp, unsigned short* __restrict__ Vt,
    const int* __restrict__ cnt) {
  __shared__ unsigned short t[64 * 72];
  const int bh = blockIdx.y, jt = blockIdx.x;
  if (cnt) {
    if (jt * 64 >= ((cnt[bh >> 3] + 63) & ~63)) return;
  }
  const int tid = threadIdx.x;
#pragma unroll
  for (int i = 0; i < 2; ++i) {
    int g = i * 256 + tid;
    int j = g >> 3, c8 = g & 7;
    *(uint4*)&t[j * 72 + c8 * 8] =
        *(const uint4*)(Vp + ((size_t)bh * Klen + jt * 64 + j) * 64 + c8 * 8);
  }
  __syncthreads();
#pragma unroll
  for (int i = 0; i < 2; ++i) {
    int g = i * 256 + tid;
    int d = g >> 3, j8 = g & 7;
    unsigned short tmp[8];
#pragma unroll
    for (int kx = 0; kx < 8; ++kx) tmp[kx] = t[(j8 * 8 + kx) * 72 + d];
    *(uint4*)(Vt + ((size_t)bh * HDim + d) * Klen + jt * 64 + j8 * 8) = *(const uint4*)tmp;
  }
}

// ============================================================
// Output projection, double-buffered staging (1 barrier/iter)
// ============================================================
__global__ __launch_bounds__(256) void gemm_out(
    const unsigned short* __restrict__ Oa,
    const unsigned short* __restrict__ Woh,
    float* __restrict__ out) {
  __shared__ unsigned short As[2][128 * 32];
  __shared__ unsigned short Bs[2][128 * 32];
  const int tid = threadIdx.x;
  const int w = tid >> 6, l = tid & 63;
  const int quad = l >> 4, l15 = l & 15;
  const int m0 = blockIdx.x * 128;
  const int n0 = blockIdx.y * 128;

  f32x4 acc[4][4] = {};
  const int lrow = l >> 2;
  const int lcol = (l & 3) * 8;
  const int wm = (w >> 1) * 64, wn = (w & 1) * 64;

  auto stage = [&](int bs, int kk) {
#pragma unroll
    for (int i = 0; i < 2; ++i) {
      int row = w * 32 + i * 16 + lrow;
      gload_lds16(Oa + (size_t)(m0 + row) * 512 + kk + lcol, &As[bs][row * 32 + lcol]);
      gload_lds16(Woh + (size_t)(n0 + row) * 512 + kk + lcol, &Bs[bs][row * 32 + lcol]);
    }
  };

  stage(0, 0);
  for (int kk = 0; kk < 512; kk += 32) {
    const int cur = (kk >> 5) & 1;
    __syncthreads();
    if (kk + 32 < 512) stage(cur ^ 1, kk + 32);
    short8 af[4], bf[4];
#pragma unroll
    for (int t = 0; t < 4; ++t)
      af[t] = *(const short8*)&As[cur][(wm + t * 16 + l15) * 32 + quad * 8];
#pragma unroll
    for (int t = 0; t < 4; ++t)
      bf[t] = *(const short8*)&Bs[cur][(wn + t * 16 + l15) * 32 + quad * 8];
#pragma unroll
    for (int mt = 0; mt < 4; ++mt)
#pragma unroll
      for (int nt = 0; nt < 4; ++nt)
        acc[mt][nt] = MFMA16(af[mt], bf[nt], acc[mt][nt]);
  }
#pragma unroll
  for (int mt = 0; mt < 4; ++mt)
#pragma unroll
    for (int nt = 0; nt < 4; ++nt)
#pragma unroll
      for (int r = 0; r < 4; ++r) {
        int m  = m0 + wm + mt * 16 + quad * 4 + r;
        int nn = n0 + wn + nt * 16 + l15;
        out[(size_t)m * 512 + nn] = acc[mt][nt][r];
      }
}

// ============================================================
// Flash attention — R2 structure restored (verified 48.5 us):
// single-buffered Ks/Vs staging, Ps LDS round-trip for P^T,
// COMPACT keys, defer-max, MFMA row-sum. setprio kept (attn+).
// ============================================================
template <bool KSPLIT, bool COMPACT>
__global__ __launch_bounds__(256, 4) void attn(
    const unsigned short* __restrict__ Qp,
    const unsigned short* __restrict__ Kp,
    const unsigned short* __restrict__ Vt,
    const float* __restrict__ biasf,
    const int* __restrict__ cntArr,
    unsigned short* __restrict__ Oa,     // SINGLE: (B,Q,D) out
    unsigned short* __restrict__ Op,     // KSPLIT: partial O [part][bh][qrow][64]
    float* __restrict__ Sp) {            // KSPLIT: logsumexp [part][bh*Qlen]
  __shared__ unsigned short Ks[64 * 64];
  __shared__ unsigned short Vs[64 * 64];
  __shared__ unsigned short Ps[4][16 * 72];

  const int tid = threadIdx.x;
  const int w = tid >> 6, l = tid & 63;
  const int quad = l >> 4, l15 = l & 15;
  const int bid = blockIdx.x;
  const int bh = bid & 31;            // same bh -> same XCD
  const int b = bh >> 3, h = bh & 7;

  int cnt, KT;
  if constexpr (COMPACT) {
    cnt = cntArr[b];
    KT = (cnt + 63) >> 6;
  } else {
    cnt = Klen;
    KT = Klen / 64;
  }

  int qt, part, kt0, ktN;
  if constexpr (KSPLIT) {
    int rest = bid >> 5;              // 0..63
    part = rest & 1;
    qt = rest >> 1;
    int half = (KT + 1) >> 1;
    kt0 = part ? half : 0;
    ktN = part ? KT : half;
  } else {
    part = 0; qt = bid >> 5; kt0 = 0; ktN = KT;
  }
  const int x = l15 & 7;
  const int qrow = qt * 64 + w * 16 + l15;

  short8 aq[2];
#pragma unroll
  for (int k2 = 0; k2 < 2; ++k2)
    aq[k2] = *(const short8*)(Qp + ((size_t)bh * Qlen + qrow) * HDim + (k2 * 4 + quad) * 8);

  short8 ones;
#pragma unroll
  for (int j = 0; j < 8; ++j) ones[j] = (short)0x3C00;  // fp16 1.0

  f32x4 o[4] = {};
  f32x4 o5 = {};                       // row-sum accumulator (l), via MFMA
  float m_run = -1.0e6f;
  const float* brow = biasf + b * Klen;  // only used when !COMPACT

  for (int kt = kt0; kt < ktN; ++kt) {
    __syncthreads();
#pragma unroll
    for (int i = 0; i < 2; ++i) {
      int g = i * 256 + tid;
      int row = g >> 3, c8 = g & 7;
      int sb = (c8 ^ (row & 7)) * 8;
      gload_lds16(Kp + ((size_t)bh * Klen + kt * 64 + row) * HDim + sb, &Ks[g * 8]);
      gload_lds16(Vt + ((size_t)bh * HDim + row) * Klen + kt * 64 + sb, &Vs[g * 8]);
    }
    float4 bb[4];
    if constexpr (!COMPACT) {
#pragma unroll
      for (int ct = 0; ct < 4; ++ct)
        bb[ct] = *(const float4*)(brow + kt * 64 + ct * 16 + quad * 4);
    }
    __syncthreads();

    // ---- S^T = K . Q^T (Q pre-scaled by C1 -> exp2 domain) ----
    f32x4 sv[4];
    __builtin_amdgcn_s_setprio(1);
#pragma unroll
    for (int ct = 0; ct < 4; ++ct) {
      const short8 bk0 = *(const short8*)&Ks[(ct * 16 + l15) * 64 + (quad ^ x) * 8];
      const short8 bk1 = *(const short8*)&Ks[(ct * 16 + l15) * 64 + ((4 + quad) ^ x) * 8];
      f32x4 a = {};
      a = MFMA16(bk0, aq[0], a);
      a = MFMA16(bk1, aq[1], a);
      sv[ct] = a;
    }
    __builtin_amdgcn_s_setprio(0);

    if constexpr (!COMPACT) {
#pragma unroll
      for (int ct = 0; ct < 4; ++ct)
#pragma unroll
        for (int r = 0; r < 4; ++r)
          sv[ct][r] += bb[ct][r];
    } else {
      if (kt == KT - 1) {  // mask the pad keys in the final tile
#pragma unroll
        for (int ct = 0; ct < 4; ++ct)
#pragma unroll
          for (int r = 0; r < 4; ++r)
            if (kt * 64 + ct * 16 + quad * 4 + r >= cnt) sv[ct][r] = -60000.0f;
      }
    }

    // ---- per-q max (cross-quad) + deferred rescale ----
    float mx0 = fmaxf(fmaxf(sv[0][0], sv[0][1]), fmaxf(sv[0][2], sv[0][3]));
    float mx1 = fmaxf(fmaxf(sv[1][0], sv[1][1]), fmaxf(sv[1][2], sv[1][3]));
    float mx2 = fmaxf(fmaxf(sv[2][0], sv[2][1]), fmaxf(sv[2][2], sv[2][3]));
    float mx3 = fmaxf(fmaxf(sv[3][0], sv[3][1]), fmaxf(sv[3][2], sv[3][3]));
    float mx = fmaxf(fmaxf(mx0, mx1), fmaxf(mx2, mx3));
    mx = fmaxf(mx, __shfl_xor(mx, 16));
    mx = fmaxf(mx, __shfl_xor(mx, 32));
    if (__any(mx > m_run + 8.0f)) {
      float mnew  = fmaxf(m_run, mx);
      float alpha = exp2f(m_run - mnew);
      m_run = mnew;
#pragma unroll
      for (int ctd = 0; ctd < 4; ++ctd) o[ctd] *= alpha;
      o5 *= alpha;
    }

    // ---- P = exp2(S - m), pack to wave-private Ps ----
#pragma unroll
    for (int ct = 0; ct < 4; ++ct) {
      float p0 = exp2f(sv[ct][0] - m_run);
      float p1 = exp2f(sv[ct][1] - m_run);
      float p2 = exp2f(sv[ct][2] - m_run);
      float p3 = exp2f(sv[ct][3] - m_run);
      unsigned pk[2] = {pk2h(p0, p1), pk2h(p2, p3)};
      *(uint2*)&Ps[w][l15 * 72 + ct * 16 + quad * 4] = *(const uint2*)pk;
    }
    const short8 ap0 = *(const short8*)&Ps[w][l15 * 72 + quad * 8];
    const short8 ap1 = *(const short8*)&Ps[w][l15 * 72 + 32 + quad * 8];

    // ---- l += ones . P^T ; O^T += V^T . P^T ----
    __builtin_amdgcn_s_setprio(1);
    o5 = MFMA16(ones, ap0, o5);
    o5 = MFMA16(ones, ap1, o5);
#pragma unroll
    for (int ctd = 0; ctd < 4; ++ctd) {
      const short8 bv0 = *(const short8*)&Vs[(ctd * 16 + l15) * 64 + (quad ^ x) * 8];
      const short8 bv1 = *(const short8*)&Vs[(ctd * 16 + l15) * 64 + ((4 + quad) ^ x) * 8];
      o[ctd] = MFMA16(bv0, ap0, o[ctd]);
      o[ctd] = MFMA16(bv1, ap1, o[ctd]);
    }
    __builtin_amdgcn_s_setprio(0);
  }

  // ---- epilogue: l is replicated in every element of o5 ----
  float lt = o5[0];
  float rl = (lt > 0.0f) ? 1.0f / lt : 0.0f;
  if constexpr (KSPLIT) {
    const size_t pbase = ((size_t)part * 32 + bh) * Qlen;  // rows of this part
    const size_t obase = (pbase + qrow) * 64;
#pragma unroll
    for (int ctd = 0; ctd < 4; ++ctd) {
      unsigned pk[2] = {pk2h(o[ctd][0] * rl, o[ctd][1] * rl),
                        pk2h(o[ctd][2] * rl, o[ctd][3] * rl)};
      *(uint2*)(Op + obase + ctd * 16 + quad * 4) = *(const uint2*)pk;
    }
    if (l < 16)  // one lane per q-row (quad==0)
      Sp[pbase + qrow] = (lt > 0.0f) ? m_run + log2f(lt) : -1.0e30f;
  } else {
    const size_t obase = ((size_t)(b * Qlen) + qrow) * Dm + h * 64;
#pragma unroll
    for (int ctd = 0; ctd < 4; ++ctd) {
      unsigned pk[2] = {pk2h(o[ctd][0] * rl, o[ctd][1] * rl),
                        pk2h(o[ctd][2] * rl, o[ctd][3] * rl)};
      *(uint2*)(Oa + obase + ctd * 16 + quad * 4) = *(const uint2*)pk;
    }
  }
}

// ============================================================
// reduce_o: combine the 2 K-split partials -> Oa (B,Q,D) fp16
// ============================================================
__global__ __launch_bounds__(256) void reduce_o(
    const unsigned short* __restrict__ Op, const float* __restrict__ Sp,
    unsigned short* __restrict__ Oa) {
  int g = blockIdx.x * 256 + threadIdx.x;
  int row = g >> 3, c8 = g & 7;              // row = bh*Qlen + qrow
  const size_t PART = (size_t)32 * Qlen;     // rows per part
  float s1 = Sp[row], s2 = Sp[PART + row];
  float M = fmaxf(s1, s2);
  float w1 = exp2f(s1 - M), w2 = exp2f(s2 - M);
  float rs = 1.0f / (w1 + w2);
  w1 *= rs; w2 *= rs;
  short8 a = *(const short8*)(Op + (size_t)row * 64 + c8 * 8);
  short8 bvec = *(const short8*)(Op + (PART + row) * 64 + c8 * 8);
  half8 af = __builtin_bit_cast(half8, a);
  half8 bf = __builtin_bit_cast(half8, bvec);
  unsigned pk[4];
#pragma unroll
  for (int i = 0; i < 4; ++i) {
    float r0 = w1 * (float)af[i * 2 + 0] + w2 * (float)bf[i * 2 + 0];
    float r1 = w1 * (float)af[i * 2 + 1] + w2 * (float)bf[i * 2 + 1];
    pk[i] = pk2h(r0, r1);
  }
  int bh = row >> 11, qrow = row & 2047;
  int b = bh >> 3, h = bh & 7;
  *(uint4*)(Oa + ((size_t)(b * Qlen) + qrow) * Dm + h * 64 + c8 * 8) =
      *(const uint4*)pk;
}

extern "C" void kernel_launch(void* const* d_in, const int* in_sizes, int n_in,
                              void* d_out, int out_size, void* d_ws, size_t ws_size,
                              hipStream_t stream) {
  const float* q  = (const float*)d_in[0];
  const float* k  = (const float*)d_in[1];
  const float* v  = (const float*)d_in[2];
  const float* Wq = (const float*)d_in[3];
  const float* Wk = (const float*)d_in[4];
  const float* Wv = (const float*)d_in[5];
  const float* Wo = (const float*)d_in[6];
  const int*  msk = (const int*)d_in[7];
  float* out = (float*)d_out;

  char* ws = (char*)d_ws;
  const size_t SEG  = (size_t)Bc * Hh * Qlen * HDim * sizeof(unsigned short); // 8 MB
  const size_t WSEG = (size_t)Dm * Dm * sizeof(unsigned short);               // 0.5 MB
  unsigned short* Qp  = (unsigned short*)(ws);
  unsigned short* Kp  = (unsigned short*)(ws + SEG);
  unsigned short* Vp  = (unsigned short*)(ws + 2 * SEG);
  unsigned short* Vt  = (unsigned short*)(ws + 3 * SEG);
  unsigned short* Oa  = Vp;  // Vp dead after transpose_v
  unsigned short* Wqh = (unsigned short*)(ws + 4 * SEG);
  unsigned short* Wkh = (unsigned short*)(ws + 4 * SEG + WSEG);
  unsigned short* Wvh = (unsigned short*)(ws + 4 * SEG + 2 * WSEG);
  unsigned short* Woh = (unsigned short*)(ws + 4 * SEG + 3 * WSEG);
  // 64 KB region: big path = idx (32 KB) + cnt; small path = f32 bias (32 KB)
  int*   idxArr = (int*)(ws + 4 * SEG + 4 * WSEG);
  int*   cntArr = idxArr + Bc * Klen;
  float* Bfs    = (float*)idxArr;
  unsigned short* qh  = (unsigned short*)(ws + 4 * SEG + 4 * WSEG + 65536);
  unsigned short* kh  = qh + SEG / 2;
  unsigned short* vh  = kh + SEG / 2;
  // K-split partials alias qh/kh (dead after gemm_qkv); Sp aliases vh.
  unsigned short* Op  = qh;                  // 2 parts x 8 MB
  float*          Sp  = (float*)vh;          // 2 x 64K floats = 512 KB
  const size_t NEED = 4 * SEG + 4 * WSEG + 65536 + 3 * SEG;
  const bool big = ws_size >= NEED;

  // bind multi-arg template instantiations outside the launch macro
  auto attn_split  = attn<true, true>;
  auto attn_single = attn<false, false>;

  const int wn = Dm * Dm;
  if (big) {
    hipLaunchKernelGGL(scan_mask, dim3(Bc), dim3(256), 0, stream, msk, idxArr, cntArr);
    hipLaunchKernelGGL(cvt4, dim3(wn / 1024, 4), dim3(256), 0, stream,
                       Wq, Wk, Wv, Wo, Wqh, Wkh, Wvh, Woh, msk, Bfs);
    hipLaunchKernelGGL(cvt_in, dim3(4096, 3), dim3(256), 0, stream,
                       q, k, v, qh, kh, vh, idxArr, cntArr);
    hipLaunchKernelGGL(gemm_qkv<true>, dim3(64, 12), dim3(256), 0, stream,
                       q, k, v, qh, kh, vh, Wqh, Wkh, Wvh, Qp, Kp, Vp, cntArr);
    hipLaunchKernelGGL(transpose_v, dim3(32, 32), dim3(256), 0, stream, Vp, Vt, cntArr);
    hipLaunchKernelGGL(attn_split, dim3(2048), dim3(256), 0, stream,
                       Qp, Kp, Vt, Bfs, cntArr, Oa, Op, Sp);
    hipLaunchKernelGGL(reduce_o, dim3(2048), dim3(256), 0, stream, Op, Sp, Oa);
  } else {
    hipLaunchKernelGGL(cvt4, dim3(wn / 1024, 5), dim3(256), 0, stream,
                       Wq, Wk, Wv, Wo, Wqh, Wkh, Wvh, Woh, msk, Bfs);
    hipLaunchKernelGGL(gemm_qkv<false>, dim3(64, 12), dim3(256), 0, stream,
                       q, k, v, qh, kh, vh, Wqh, Wkh, Wvh, Qp, Kp, Vp, cntArr);
    hipLaunchKernelGGL(transpose_v, dim3(32, 32), dim3(256), 0, stream, Vp, Vt,
                       (const int*)nullptr);
    hipLaunchKernelGGL(attn_single, dim3(1024), dim3(256), 0, stream,
                       Qp, Kp, Vt, Bfs, (const int*)nullptr, Oa, Op, Sp);
  }
  hipLaunchKernelGGL(gemm_out, dim3(64, 4), dim3(256), 0, stream, Oa, Woh, out);
}

// Round 8
// 184.171 us; speedup vs baseline: 1.2540x; 1.0309x over previous
//
#include <hip/hip_runtime.h>

// ---- problem constants ----
constexpr int Bc   = 4;
constexpr int Qlen = 2048;
constexpr int Klen = 2048;
constexpr int Dm   = 512;
constexpr int Hh   = 8;
constexpr int HDim = 64;
constexpr float C1 = 0.125f * 1.4426950408889634f;  // attn scale * log2(e), folded into Qp

typedef __attribute__((ext_vector_type(8))) short short8;       // 8x16-bit storage
typedef __attribute__((ext_vector_type(8))) _Float16 half8;     // fp16 MFMA frag
typedef __attribute__((ext_vector_type(2))) __fp16 fp16x2;      // cvt_pkrtz result
typedef __attribute__((ext_vector_type(4))) float f32x4;

__device__ __forceinline__ f32x4 MFMA16(short8 a, short8 b, f32x4 c) {
  return __builtin_amdgcn_mfma_f32_16x16x32_f16(
      __builtin_bit_cast(half8, a), __builtin_bit_cast(half8, b), c, 0, 0, 0);
}

__device__ __forceinline__ void gload_lds16(const void* g, void* l) {
  __builtin_amdgcn_global_load_lds(
      (const __attribute__((address_space(1))) void*)g,
      (__attribute__((address_space(3))) void*)l, 16, 0, 0);
}

__device__ __forceinline__ unsigned short f2h(float f) {
  _Float16 h = (_Float16)f;
  return __builtin_bit_cast(unsigned short, h);
}

__device__ __forceinline__ unsigned pk2h(float a, float b) {
  fp16x2 h = __builtin_amdgcn_cvt_pkrtz(a, b);
  return __builtin_bit_cast(unsigned, h);
}

// ============================================================
// scan_mask: per-batch compaction of unmasked key indices.
// ============================================================
__global__ __launch_bounds__(256) void scan_mask(
    const int* __restrict__ msk, int* __restrict__ idx, int* __restrict__ cnt) {
  const int b = blockIdx.x;
  const int tid = threadIdx.x;
  __shared__ int wtot[4];
  const int* mrow = msk + b * Klen;
  int m8[8];
  int c = 0;
#pragma unroll
  for (int i = 0; i < 8; ++i) {
    m8[i] = mrow[tid * 8 + i];
    c += (m8[i] != 0);
  }
  int pre = c;  // inclusive prefix within wave
#pragma unroll
  for (int off = 1; off < 64; off <<= 1) {
    int t = __shfl_up(pre, off);
    if ((tid & 63) >= off) pre += t;
  }
  const int w = tid >> 6;
  if ((tid & 63) == 63) wtot[w] = pre;
  __syncthreads();
  int base = 0;
  for (int i = 0; i < w; ++i) base += wtot[i];
  int p = base + pre - c;  // exclusive prefix for this thread
#pragma unroll
  for (int i = 0; i < 8; ++i)
    if (m8[i] != 0) idx[b * Klen + (p++)] = tid * 8 + i;
  if (tid == 255) cnt[b] = base + pre;
}

// ============================================================
// cvt4: f32->fp16 of the 4 weight matrices (+ mask bias, fallback path)
// ============================================================
__global__ __launch_bounds__(256) void cvt4(
    const float* __restrict__ s0, const float* __restrict__ s1,
    const float* __restrict__ s2, const float* __restrict__ s3,
    unsigned short* __restrict__ o0, unsigned short* __restrict__ o1,
    unsigned short* __restrict__ o2, unsigned short* __restrict__ o3,
    const int* __restrict__ msk, float* __restrict__ biasf) {
  const int seg = blockIdx.y;
  int i = (blockIdx.x * 256 + threadIdx.x) * 4;
  if (seg < 4) {
    const float* s = (seg == 0) ? s0 : (seg == 1) ? s1 : (seg == 2) ? s2 : s3;
    unsigned short* o = (seg == 0) ? o0 : (seg == 1) ? o1 : (seg == 2) ? o2 : o3;
    float4 x = *(const float4*)(s + i);
    unsigned t[2] = {pk2h(x.x, x.y), pk2h(x.z, x.w)};
    *(uint2*)(o + i) = *(const uint2*)t;
  } else if (i + 3 < Bc * Klen) {
    int4 m = *(const int4*)(msk + i);
    float4 bo;
    bo.x = (m.x == 0) ? -60000.0f : 0.0f;
    bo.y = (m.y == 0) ? -60000.0f : 0.0f;
    bo.z = (m.z == 0) ? -60000.0f : 0.0f;
    bo.w = (m.w == 0) ? -60000.0f : 0.0f;
    *(float4*)(biasf + i) = bo;
  }
}

// ============================================================
// cvt_in: f32->fp16. seg 0 = Q copy; segs 1,2 = K,V row-gather.
// ============================================================
__global__ __launch_bounds__(256) void cvt_in(
    const float* __restrict__ q, const float* __restrict__ k,
    const float* __restrict__ v,
    unsigned short* __restrict__ qh, unsigned short* __restrict__ kh,
    unsigned short* __restrict__ vh,
    const int* __restrict__ idx, const int* __restrict__ cnt) {
  const int seg = blockIdx.y;
  int g = blockIdx.x * 256 + threadIdx.x;
  int i = g * 4;
  if (seg == 0) {
    float4 x = *(const float4*)(q + i);
    unsigned t[2] = {pk2h(x.x, x.y), pk2h(x.z, x.w)};
    *(uint2*)(qh + i) = *(const uint2*)t;
    return;
  }
  const float* s = (seg == 1) ? k : v;
  unsigned short* o = (seg == 1) ? kh : vh;
  int row = i >> 9, col = i & 511;
  int b = row >> 11, jc = row & 2047;
  int cb = cnt[b];
  if (jc < cb) {
    int j = idx[b * Klen + jc];
    float4 x = *(const float4*)(s + ((size_t)(b * Klen + j)) * 512 + col);
    unsigned t[2] = {pk2h(x.x, x.y), pk2h(x.z, x.w)};
    *(uint2*)(o + (size_t)row * 512 + col) = *(const uint2*)t;
  } else if (jc < ((cb + 127) & ~127)) {
    uint2 z = {0u, 0u};
    *(uint2*)(o + (size_t)row * 512 + col) = z;
  }
}

// ============================================================
// Fused QKV projection, double-buffered staging (1 barrier/iter).
// Q output pre-scaled by C1.
// ============================================================
template <bool F16A>
__global__ __launch_bounds__(256) void gemm_qkv(
    const float* __restrict__ q_in,
    const float* __restrict__ k_in,
    const float* __restrict__ v_in,
    const unsigned short* __restrict__ qh,
    const unsigned short* __restrict__ kh,
    const unsigned short* __restrict__ vh,
    const unsigned short* __restrict__ Wqh,
    const unsigned short* __restrict__ Wkh,
    const unsigned short* __restrict__ Wvh,
    unsigned short* __restrict__ Qp,
    unsigned short* __restrict__ Kp,
    unsigned short* __restrict__ Vp,
    const int* __restrict__ cnt) {
  __shared__ unsigned short As[2][128 * 32];
  __shared__ unsigned short Bs[2][128 * 32];
  const int tid = threadIdx.x;
  const int w = tid >> 6, l = tid & 63;
  const int quad = l >> 4, l15 = l & 15;
  const int m0 = blockIdx.x * 128;
  const int n0 = blockIdx.y * 128;
  const int seg = n0 >> 9;
  const int f0  = n0 & 511;
  if constexpr (F16A) {
    if (seg != 0) {
      int local = m0 & 2047;
      if (local >= ((cnt[m0 >> 11] + 63) & ~63)) return;
    }
  }
  const float* Af = (seg == 0) ? q_in : (seg == 1) ? k_in : v_in;
  const unsigned short* Ah = (seg == 0) ? qh : (seg == 1) ? kh : vh;
  const unsigned short* W = (seg == 0) ? Wqh : (seg == 1) ? Wkh : Wvh;
  unsigned short* dst = (seg == 0) ? Qp : (seg == 1) ? Kp : Vp;

  f32x4 acc[4][4] = {};
  const int lrow = l >> 2;
  const int lcol = (l & 3) * 8;
  const int wm = (w >> 1) * 64, wn = (w & 1) * 64;

  auto stage = [&](int bs, int kk) {
#pragma unroll
    for (int i = 0; i < 2; ++i) {
      int row = w * 32 + i * 16 + lrow;
      if constexpr (F16A) {
        gload_lds16(Ah + (size_t)(m0 + row) * 512 + kk + lcol, &As[bs][row * 32 + lcol]);
      } else {
        const float* ap = Af + (size_t)(m0 + row) * 512 + kk + lcol;
        float4 x0 = *(const float4*)(ap);
        float4 x1 = *(const float4*)(ap + 4);
        unsigned t[4] = {pk2h(x0.x, x0.y), pk2h(x0.z, x0.w),
                         pk2h(x1.x, x1.y), pk2h(x1.z, x1.w)};
        *(uint4*)&As[bs][row * 32 + lcol] = *(const uint4*)t;
      }
      gload_lds16(W + (size_t)(f0 + row) * 512 + kk + lcol, &Bs[bs][row * 32 + lcol]);
    }
  };

  stage(0, 0);
  for (int kk = 0; kk < 512; kk += 32) {
    const int cur = (kk >> 5) & 1;
    __syncthreads();                 // drains vmcnt: stage(cur) complete
    if (kk + 32 < 512) stage(cur ^ 1, kk + 32);  // prefetch next, hidden under MFMA
    short8 af[4], bf[4];
#pragma unroll
    for (int t = 0; t < 4; ++t)
      af[t] = *(const short8*)&As[cur][(wm + t * 16 + l15) * 32 + quad * 8];
#pragma unroll
    for (int t = 0; t < 4; ++t)
      bf[t] = *(const short8*)&Bs[cur][(wn + t * 16 + l15) * 32 + quad * 8];
#pragma unroll
    for (int mt = 0; mt < 4; ++mt)
#pragma unroll
      for (int nt = 0; nt < 4; ++nt)
        acc[mt][nt] = MFMA16(af[mt], bf[nt], acc[mt][nt]);
  }
  const float oscale = (seg == 0) ? C1 : 1.0f;
#pragma unroll
  for (int mt = 0; mt < 4; ++mt)
#pragma unroll
    for (int nt = 0; nt < 4; ++nt)
#pragma unroll
      for (int r = 0; r < 4; ++r) {
        int m  = m0 + wm + mt * 16 + quad * 4 + r;
        int nn = f0 + wn + nt * 16 + l15;
        int b = m >> 11, qq = m & 2047;
        int h = nn >> 6, hd = nn & 63;
        dst[(((size_t)(b * Hh + h)) * Qlen + qq) * HDim + hd] =
            f2h(acc[mt][nt][r] * oscale);
      }
}

// ============================================================
// V transpose (cnt != nullptr: skip tiles beyond padded key count)
// ============================================================
__global__ __launch_bounds__(256) void transpose_v(
    const unsigned short* __restrict__ Vp, unsigned short* __restrict__ Vt,
    const int* __restrict__ cnt) {
  __shared__ unsigned short t[64 * 72];
  const int bh = blockIdx.y, jt = blockIdx.x;
  if (cnt) {
    if (jt * 64 >= ((cnt[bh >> 3] + 63) & ~63)) return;
  }
  const int tid = threadIdx.x;
#pragma unroll
  for (int i = 0; i < 2; ++i) {
    int g = i * 256 + tid;
    int j = g >> 3, c8 = g & 7;
    *(uint4*)&t[j * 72 + c8 * 8] =
        *(const uint4*)(Vp + ((size_t)bh * Klen + jt * 64 + j) * 64 + c8 * 8);
  }
  __syncthreads();
#pragma unroll
  for (int i = 0; i < 2; ++i) {
    int g = i * 256 + tid;
    int d = g >> 3, j8 = g & 7;
    unsigned short tmp[8];
#pragma unroll
    for (int kx = 0; kx < 8; ++kx) tmp[kx] = t[(j8 * 8 + kx) * 72 + d];
    *(uint4*)(Vt + ((size_t)bh * HDim + d) * Klen + jt * 64 + j8 * 8) = *(const uint4*)tmp;
  }
}

// ============================================================
// Output projection, double-buffered staging (1 barrier/iter)
// ============================================================
__global__ __launch_bounds__(256) void gemm_out(
    const unsigned short* __restrict__ Oa,
    const unsigned short* __restrict__ Woh,
    float* __restrict__ out) {
  __shared__ unsigned short As[2][128 * 32];
  __shared__ unsigned short Bs[2][128 * 32];
  const int tid = threadIdx.x;
  const int w = tid >> 6, l = tid & 63;
  const int quad = l >> 4, l15 = l & 15;
  const int m0 = blockIdx.x * 128;
  const int n0 = blockIdx.y * 128;

  f32x4 acc[4][4] = {};
  const int lrow = l >> 2;
  const int lcol = (l & 3) * 8;
  const int wm = (w >> 1) * 64, wn = (w & 1) * 64;

  auto stage = [&](int bs, int kk) {
#pragma unroll
    for (int i = 0; i < 2; ++i) {
      int row = w * 32 + i * 16 + lrow;
      gload_lds16(Oa + (size_t)(m0 + row) * 512 + kk + lcol, &As[bs][row * 32 + lcol]);
      gload_lds16(Woh + (size_t)(n0 + row) * 512 + kk + lcol, &Bs[bs][row * 32 + lcol]);
    }
  };

  stage(0, 0);
  for (int kk = 0; kk < 512; kk += 32) {
    const int cur = (kk >> 5) & 1;
    __syncthreads();
    if (kk + 32 < 512) stage(cur ^ 1, kk + 32);
    short8 af[4], bf[4];
#pragma unroll
    for (int t = 0; t < 4; ++t)
      af[t] = *(const short8*)&As[cur][(wm + t * 16 + l15) * 32 + quad * 8];
#pragma unroll
    for (int t = 0; t < 4; ++t)
      bf[t] = *(const short8*)&Bs[cur][(wn + t * 16 + l15) * 32 + quad * 8];
#pragma unroll
    for (int mt = 0; mt < 4; ++mt)
#pragma unroll
      for (int nt = 0; nt < 4; ++nt)
        acc[mt][nt] = MFMA16(af[mt], bf[nt], acc[mt][nt]);
  }
#pragma unroll
  for (int mt = 0; mt < 4; ++mt)
#pragma unroll
    for (int nt = 0; nt < 4; ++nt)
#pragma unroll
      for (int r = 0; r < 4; ++r) {
        int m  = m0 + wm + mt * 16 + quad * 4 + r;
        int nn = n0 + wn + nt * 16 + l15;
        out[(size_t)m * 512 + nn] = acc[mt][nt][r];
      }
}

// ============================================================
// Flash attention — verified R6 body. This round: launched with
// KSPLIT=false (grid 1024 = 4 blocks/CU, all co-resident), writing
// Oa directly; reduce_o eliminated. Body unchanged.
// ============================================================
template <bool KSPLIT, bool COMPACT>
__global__ __launch_bounds__(256, 4) void attn(
    const unsigned short* __restrict__ Qp,
    const unsigned short* __restrict__ Kp,
    const unsigned short* __restrict__ Vt,
    const float* __restrict__ biasf,
    const int* __restrict__ cntArr,
    unsigned short* __restrict__ Oa,     // !KSPLIT: (B,Q,D) out
    unsigned short* __restrict__ Op,     // KSPLIT: partial O [part][bh][qrow][64]
    float* __restrict__ Sp) {            // KSPLIT: logsumexp [part][bh*Qlen]
  __shared__ unsigned short Ks[64 * 64];
  __shared__ unsigned short Vs[64 * 64];
  __shared__ unsigned short Ps[4][16 * 72];

  const int tid = threadIdx.x;
  const int w = tid >> 6, l = tid & 63;
  const int quad = l >> 4, l15 = l & 15;
  const int bid = blockIdx.x;
  const int bh = bid & 31;            // same bh -> same XCD
  const int b = bh >> 3, h = bh & 7;

  int cnt, KT;
  if constexpr (COMPACT) {
    cnt = cntArr[b];
    KT = (cnt + 63) >> 6;
  } else {
    cnt = Klen;
    KT = Klen / 64;
  }

  int qt, part, kt0, ktN;
  if constexpr (KSPLIT) {
    int rest = bid >> 5;
    part = rest & 1;
    qt = rest >> 1;
    int half = (KT + 1) >> 1;
    kt0 = part ? half : 0;
    ktN = part ? KT : half;
  } else {
    part = 0; qt = bid >> 5; kt0 = 0; ktN = KT;
  }
  const int x = l15 & 7;
  const int qrow = qt * 64 + w * 16 + l15;

  short8 aq[2];
#pragma unroll
  for (int k2 = 0; k2 < 2; ++k2)
    aq[k2] = *(const short8*)(Qp + ((size_t)bh * Qlen + qrow) * HDim + (k2 * 4 + quad) * 8);

  short8 ones;
#pragma unroll
  for (int j = 0; j < 8; ++j) ones[j] = (short)0x3C00;  // fp16 1.0

  f32x4 o[4] = {};
  f32x4 o5 = {};                       // row-sum accumulator (l), via MFMA
  float m_run = -1.0e6f;
  const float* brow = biasf + b * Klen;  // only used when !COMPACT

  for (int kt = kt0; kt < ktN; ++kt) {
    __syncthreads();
#pragma unroll
    for (int i = 0; i < 2; ++i) {
      int g = i * 256 + tid;
      int row = g >> 3, c8 = g & 7;
      int sb = (c8 ^ (row & 7)) * 8;
      gload_lds16(Kp + ((size_t)bh * Klen + kt * 64 + row) * HDim + sb, &Ks[g * 8]);
      gload_lds16(Vt + ((size_t)bh * HDim + row) * Klen + kt * 64 + sb, &Vs[g * 8]);
    }
    float4 bb[4];
    if constexpr (!COMPACT) {
#pragma unroll
      for (int ct = 0; ct < 4; ++ct)
        bb[ct] = *(const float4*)(brow + kt * 64 + ct * 16 + quad * 4);
    }
    __syncthreads();

    // ---- S^T = K . Q^T (Q pre-scaled by C1 -> exp2 domain) ----
    f32x4 sv[4];
    __builtin_amdgcn_s_setprio(1);
#pragma unroll
    for (int ct = 0; ct < 4; ++ct) {
      const short8 bk0 = *(const short8*)&Ks[(ct * 16 + l15) * 64 + (quad ^ x) * 8];
      const short8 bk1 = *(const short8*)&Ks[(ct * 16 + l15) * 64 + ((4 + quad) ^ x) * 8];
      f32x4 a = {};
      a = MFMA16(bk0, aq[0], a);
      a = MFMA16(bk1, aq[1], a);
      sv[ct] = a;
    }
    __builtin_amdgcn_s_setprio(0);

    if constexpr (!COMPACT) {
#pragma unroll
      for (int ct = 0; ct < 4; ++ct)
#pragma unroll
        for (int r = 0; r < 4; ++r)
          sv[ct][r] += bb[ct][r];
    } else {
      if (kt == KT - 1) {  // mask the pad keys in the final tile
#pragma unroll
        for (int ct = 0; ct < 4; ++ct)
#pragma unroll
          for (int r = 0; r < 4; ++r)
            if (kt * 64 + ct * 16 + quad * 4 + r >= cnt) sv[ct][r] = -60000.0f;
      }
    }

    // ---- per-q max (cross-quad) + deferred rescale ----
    float mx0 = fmaxf(fmaxf(sv[0][0], sv[0][1]), fmaxf(sv[0][2], sv[0][3]));
    float mx1 = fmaxf(fmaxf(sv[1][0], sv[1][1]), fmaxf(sv[1][2], sv[1][3]));
    float mx2 = fmaxf(fmaxf(sv[2][0], sv[2][1]), fmaxf(sv[2][2], sv[2][3]));
    float mx3 = fmaxf(fmaxf(sv[3][0], sv[3][1]), fmaxf(sv[3][2], sv[3][3]));
    float mx = fmaxf(fmaxf(mx0, mx1), fmaxf(mx2, mx3));
    mx = fmaxf(mx, __shfl_xor(mx, 16));
    mx = fmaxf(mx, __shfl_xor(mx, 32));
    if (__any(mx > m_run + 8.0f)) {
      float mnew  = fmaxf(m_run, mx);
      float alpha = exp2f(m_run - mnew);
      m_run = mnew;
#pragma unroll
      for (int ctd = 0; ctd < 4; ++ctd) o[ctd] *= alpha;
      o5 *= alpha;
    }

    // ---- P = exp2(S - m), pack to wave-private Ps ----
#pragma unroll
    for (int ct = 0; ct < 4; ++ct) {
      float p0 = exp2f(sv[ct][0] - m_run);
      float p1 = exp2f(sv[ct][1] - m_run);
      float p2 = exp2f(sv[ct][2] - m_run);
      float p3 = exp2f(sv[ct][3] - m_run);
      unsigned pk[2] = {pk2h(p0, p1), pk2h(p2, p3)};
      *(uint2*)&Ps[w][l15 * 72 + ct * 16 + quad * 4] = *(const uint2*)pk;
    }
    const short8 ap0 = *(const short8*)&Ps[w][l15 * 72 + quad * 8];
    const short8 ap1 = *(const short8*)&Ps[w][l15 * 72 + 32 + quad * 8];

    // ---- l += ones . P^T ; O^T += V^T . P^T ----
    __builtin_amdgcn_s_setprio(1);
    o5 = MFMA16(ones, ap0, o5);
    o5 = MFMA16(ones, ap1, o5);
#pragma unroll
    for (int ctd = 0; ctd < 4; ++ctd) {
      const short8 bv0 = *(const short8*)&Vs[(ctd * 16 + l15) * 64 + (quad ^ x) * 8];
      const short8 bv1 = *(const short8*)&Vs[(ctd * 16 + l15) * 64 + ((4 + quad) ^ x) * 8];
      o[ctd] = MFMA16(bv0, ap0, o[ctd]);
      o[ctd] = MFMA16(bv1, ap1, o[ctd]);
    }
    __builtin_amdgcn_s_setprio(0);
  }

  // ---- epilogue: l is replicated in every element of o5 ----
  float lt = o5[0];
  float rl = (lt > 0.0f) ? 1.0f / lt : 0.0f;
  if constexpr (KSPLIT) {
    const size_t pbase = ((size_t)part * 32 + bh) * Qlen;
    const size_t obase = (pbase + qrow) * 64;
#pragma unroll
    for (int ctd = 0; ctd < 4; ++ctd) {
      unsigned pk[2] = {pk2h(o[ctd][0] * rl, o[ctd][1] * rl),
                        pk2h(o[ctd][2] * rl, o[ctd][3] * rl)};
      *(uint2*)(Op + obase + ctd * 16 + quad * 4) = *(const uint2*)pk;
    }
    if (l < 16)
      Sp[pbase + qrow] = (lt > 0.0f) ? m_run + log2f(lt) : -1.0e30f;
  } else {
    const size_t obase = ((size_t)(b * Qlen) + qrow) * Dm + h * 64;
#pragma unroll
    for (int ctd = 0; ctd < 4; ++ctd) {
      unsigned pk[2] = {pk2h(o[ctd][0] * rl, o[ctd][1] * rl),
                        pk2h(o[ctd][2] * rl, o[ctd][3] * rl)};
      *(uint2*)(Oa + obase + ctd * 16 + quad * 4) = *(const uint2*)pk;
    }
  }
}

extern "C" void kernel_launch(void* const* d_in, const int* in_sizes, int n_in,
                              void* d_out, int out_size, void* d_ws, size_t ws_size,
                              hipStream_t stream) {
  const float* q  = (const float*)d_in[0];
  const float* k  = (const float*)d_in[1];
  const float* v  = (const float*)d_in[2];
  const float* Wq = (const float*)d_in[3];
  const float* Wk = (const float*)d_in[4];
  const float* Wv = (const float*)d_in[5];
  const float* Wo = (const float*)d_in[6];
  const int*  msk = (const int*)d_in[7];
  float* out = (float*)d_out;

  char* ws = (char*)d_ws;
  const size_t SEG  = (size_t)Bc * Hh * Qlen * HDim * sizeof(unsigned short); // 8 MB
  const size_t WSEG = (size_t)Dm * Dm * sizeof(unsigned short);               // 0.5 MB
  unsigned short* Qp  = (unsigned short*)(ws);
  unsigned short* Kp  = (unsigned short*)(ws + SEG);
  unsigned short* Vp  = (unsigned short*)(ws + 2 * SEG);
  unsigned short* Vt  = (unsigned short*)(ws + 3 * SEG);
  unsigned short* Oa  = Vp;  // Vp dead after transpose_v; attn writes (B,Q,D) here
  unsigned short* Wqh = (unsigned short*)(ws + 4 * SEG);
  unsigned short* Wkh = (unsigned short*)(ws + 4 * SEG + WSEG);
  unsigned short* Wvh = (unsigned short*)(ws + 4 * SEG + 2 * WSEG);
  unsigned short* Woh = (unsigned short*)(ws + 4 * SEG + 3 * WSEG);
  // 64 KB region: big path = idx (32 KB) + cnt; small path = f32 bias (32 KB)
  int*   idxArr = (int*)(ws + 4 * SEG + 4 * WSEG);
  int*   cntArr = idxArr + Bc * Klen;
  float* Bfs    = (float*)idxArr;
  unsigned short* qh  = (unsigned short*)(ws + 4 * SEG + 4 * WSEG + 65536);
  unsigned short* kh  = qh + SEG / 2;
  unsigned short* vh  = kh + SEG / 2;
  const size_t NEED = 4 * SEG + 4 * WSEG + 65536 + 3 * SEG;
  const bool big = ws_size >= NEED;

  // bind multi-arg template instantiations outside the launch macro
  auto attn_one    = attn<false, true>;
  auto attn_single = attn<false, false>;

  const int wn = Dm * Dm;
  if (big) {
    hipLaunchKernelGGL(scan_mask, dim3(Bc), dim3(256), 0, stream, msk, idxArr, cntArr);
    hipLaunchKernelGGL(cvt4, dim3(wn / 1024, 4), dim3(256), 0, stream,
                       Wq, Wk, Wv, Wo, Wqh, Wkh, Wvh, Woh, msk, Bfs);
    hipLaunchKernelGGL(cvt_in, dim3(4096, 3), dim3(256), 0, stream,
                       q, k, v, qh, kh, vh, idxArr, cntArr);
    hipLaunchKernelGGL(gemm_qkv<true>, dim3(64, 12), dim3(256), 0, stream,
                       q, k, v, qh, kh, vh, Wqh, Wkh, Wvh, Qp, Kp, Vp, cntArr);
    hipLaunchKernelGGL(transpose_v, dim3(32, 32), dim3(256), 0, stream, Vp, Vt, cntArr);
    hipLaunchKernelGGL(attn_one, dim3(1024), dim3(256), 0, stream,
                       Qp, Kp, Vt, Bfs, cntArr, Oa,
                       (unsigned short*)nullptr, (float*)nullptr);
  } else {
    hipLaunchKernelGGL(cvt4, dim3(wn / 1024, 5), dim3(256), 0, stream,
                       Wq, Wk, Wv, Wo, Wqh, Wkh, Wvh, Woh, msk, Bfs);
    hipLaunchKernelGGL(gemm_qkv<false>, dim3(64, 12), dim3(256), 0, stream,
                       q, k, v, qh, kh, vh, Wqh, Wkh, Wvh, Qp, Kp, Vp, cntArr);
    hipLaunchKernelGGL(transpose_v, dim3(32, 32), dim3(256), 0, stream, Vp, Vt,
                       (const int*)nullptr);
    hipLaunchKernelGGL(attn_single, dim3(1024), dim3(256), 0, stream,
                       Qp, Kp, Vt, Bfs, (const int*)nullptr, Oa,
                       (unsigned short*)nullptr, (float*)nullptr);
  }
  hipLaunchKernelGGL(gemm_out, dim3(64, 4), dim3(256), 0, stream, Oa, Woh, out);
}

// Round 9
// 181.331 us; speedup vs baseline: 1.2737x; 1.0157x over previous
//
#include <hip/hip_runtime.h>

// ---- problem constants ----
constexpr int Bc   = 4;
constexpr int Qlen = 2048;
constexpr int Klen = 2048;
constexpr int Dm   = 512;
constexpr int Hh   = 8;
constexpr int HDim = 64;
constexpr float C1 = 0.125f * 1.4426950408889634f;  // attn scale * log2(e), folded into Qp

typedef __attribute__((ext_vector_type(8))) short short8;       // 8x16-bit storage
typedef __attribute__((ext_vector_type(8))) _Float16 half8;     // fp16 MFMA frag
typedef __attribute__((ext_vector_type(2))) __fp16 fp16x2;      // cvt_pkrtz result
typedef __attribute__((ext_vector_type(4))) float f32x4;

__device__ __forceinline__ f32x4 MFMA16(short8 a, short8 b, f32x4 c) {
  return __builtin_amdgcn_mfma_f32_16x16x32_f16(
      __builtin_bit_cast(half8, a), __builtin_bit_cast(half8, b), c, 0, 0, 0);
}

__device__ __forceinline__ void gload_lds16(const void* g, void* l) {
  __builtin_amdgcn_global_load_lds(
      (const __attribute__((address_space(1))) void*)g,
      (__attribute__((address_space(3))) void*)l, 16, 0, 0);
}

__device__ __forceinline__ unsigned short f2h(float f) {
  _Float16 h = (_Float16)f;
  return __builtin_bit_cast(unsigned short, h);
}

__device__ __forceinline__ unsigned pk2h(float a, float b) {
  fp16x2 h = __builtin_amdgcn_cvt_pkrtz(a, b);
  return __builtin_bit_cast(unsigned, h);
}

// ============================================================
// scan_mask: per-batch compaction of unmasked key indices.
// ============================================================
__global__ __launch_bounds__(256) void scan_mask(
    const int* __restrict__ msk, int* __restrict__ idx, int* __restrict__ cnt) {
  const int b = blockIdx.x;
  const int tid = threadIdx.x;
  __shared__ int wtot[4];
  const int* mrow = msk + b * Klen;
  int m8[8];
  int c = 0;
#pragma unroll
  for (int i = 0; i < 8; ++i) {
    m8[i] = mrow[tid * 8 + i];
    c += (m8[i] != 0);
  }
  int pre = c;  // inclusive prefix within wave
#pragma unroll
  for (int off = 1; off < 64; off <<= 1) {
    int t = __shfl_up(pre, off);
    if ((tid & 63) >= off) pre += t;
  }
  const int w = tid >> 6;
  if ((tid & 63) == 63) wtot[w] = pre;
  __syncthreads();
  int base = 0;
  for (int i = 0; i < w; ++i) base += wtot[i];
  int p = base + pre - c;  // exclusive prefix for this thread
#pragma unroll
  for (int i = 0; i < 8; ++i)
    if (m8[i] != 0) idx[b * Klen + (p++)] = tid * 8 + i;
  if (tid == 255) cnt[b] = base + pre;
}

// ============================================================
// cvt4: f32->fp16 of the 4 weight matrices (+ mask bias, fallback path)
// ============================================================
__global__ __launch_bounds__(256) void cvt4(
    const float* __restrict__ s0, const float* __restrict__ s1,
    const float* __restrict__ s2, const float* __restrict__ s3,
    unsigned short* __restrict__ o0, unsigned short* __restrict__ o1,
    unsigned short* __restrict__ o2, unsigned short* __restrict__ o3,
    const int* __restrict__ msk, float* __restrict__ biasf) {
  const int seg = blockIdx.y;
  int i = (blockIdx.x * 256 + threadIdx.x) * 4;
  if (seg < 4) {
    const float* s = (seg == 0) ? s0 : (seg == 1) ? s1 : (seg == 2) ? s2 : s3;
    unsigned short* o = (seg == 0) ? o0 : (seg == 1) ? o1 : (seg == 2) ? o2 : o3;
    float4 x = *(const float4*)(s + i);
    unsigned t[2] = {pk2h(x.x, x.y), pk2h(x.z, x.w)};
    *(uint2*)(o + i) = *(const uint2*)t;
  } else if (i + 3 < Bc * Klen) {
    int4 m = *(const int4*)(msk + i);
    float4 bo;
    bo.x = (m.x == 0) ? -60000.0f : 0.0f;
    bo.y = (m.y == 0) ? -60000.0f : 0.0f;
    bo.z = (m.z == 0) ? -60000.0f : 0.0f;
    bo.w = (m.w == 0) ? -60000.0f : 0.0f;
    *(float4*)(biasf + i) = bo;
  }
}

// ============================================================
// cvt_in: f32->fp16. seg 0 = Q copy; segs 1,2 = K,V row-gather.
// ============================================================
__global__ __launch_bounds__(256) void cvt_in(
    const float* __restrict__ q, const float* __restrict__ k,
    const float* __restrict__ v,
    unsigned short* __restrict__ qh, unsigned short* __restrict__ kh,
    unsigned short* __restrict__ vh,
    const int* __restrict__ idx, const int* __restrict__ cnt) {
  const int seg = blockIdx.y;
  int g = blockIdx.x * 256 + threadIdx.x;
  int i = g * 4;
  if (seg == 0) {
    float4 x = *(const float4*)(q + i);
    unsigned t[2] = {pk2h(x.x, x.y), pk2h(x.z, x.w)};
    *(uint2*)(qh + i) = *(const uint2*)t;
    return;
  }
  const float* s = (seg == 1) ? k : v;
  unsigned short* o = (seg == 1) ? kh : vh;
  int row = i >> 9, col = i & 511;
  int b = row >> 11, jc = row & 2047;
  int cb = cnt[b];
  if (jc < cb) {
    int j = idx[b * Klen + jc];
    float4 x = *(const float4*)(s + ((size_t)(b * Klen + j)) * 512 + col);
    unsigned t[2] = {pk2h(x.x, x.y), pk2h(x.z, x.w)};
    *(uint2*)(o + (size_t)row * 512 + col) = *(const uint2*)t;
  } else if (jc < ((cb + 127) & ~127)) {
    uint2 z = {0u, 0u};
    *(uint2*)(o + (size_t)row * 512 + col) = z;
  }
}

// ============================================================
// Fused QKV projection, double-buffered staging (1 barrier/iter).
// Q output pre-scaled by C1.
// ============================================================
template <bool F16A>
__global__ __launch_bounds__(256) void gemm_qkv(
    const float* __restrict__ q_in,
    const float* __restrict__ k_in,
    const float* __restrict__ v_in,
    const unsigned short* __restrict__ qh,
    const unsigned short* __restrict__ kh,
    const unsigned short* __restrict__ vh,
    const unsigned short* __restrict__ Wqh,
    const unsigned short* __restrict__ Wkh,
    const unsigned short* __restrict__ Wvh,
    unsigned short* __restrict__ Qp,
    unsigned short* __restrict__ Kp,
    unsigned short* __restrict__ Vp,
    const int* __restrict__ cnt) {
  __shared__ unsigned short As[2][128 * 32];
  __shared__ unsigned short Bs[2][128 * 32];
  const int tid = threadIdx.x;
  const int w = tid >> 6, l = tid & 63;
  const int quad = l >> 4, l15 = l & 15;
  const int m0 = blockIdx.x * 128;
  const int n0 = blockIdx.y * 128;
  const int seg = n0 >> 9;
  const int f0  = n0 & 511;
  if constexpr (F16A) {
    if (seg != 0) {
      int local = m0 & 2047;
      if (local >= ((cnt[m0 >> 11] + 63) & ~63)) return;
    }
  }
  const float* Af = (seg == 0) ? q_in : (seg == 1) ? k_in : v_in;
  const unsigned short* Ah = (seg == 0) ? qh : (seg == 1) ? kh : vh;
  const unsigned short* W = (seg == 0) ? Wqh : (seg == 1) ? Wkh : Wvh;
  unsigned short* dst = (seg == 0) ? Qp : (seg == 1) ? Kp : Vp;

  f32x4 acc[4][4] = {};
  const int lrow = l >> 2;
  const int lcol = (l & 3) * 8;
  const int wm = (w >> 1) * 64, wn = (w & 1) * 64;

  auto stage = [&](int bs, int kk) {
#pragma unroll
    for (int i = 0; i < 2; ++i) {
      int row = w * 32 + i * 16 + lrow;
      if constexpr (F16A) {
        gload_lds16(Ah + (size_t)(m0 + row) * 512 + kk + lcol, &As[bs][row * 32 + lcol]);
      } else {
        const float* ap = Af + (size_t)(m0 + row) * 512 + kk + lcol;
        float4 x0 = *(const float4*)(ap);
        float4 x1 = *(const float4*)(ap + 4);
        unsigned t[4] = {pk2h(x0.x, x0.y), pk2h(x0.z, x0.w),
                         pk2h(x1.x, x1.y), pk2h(x1.z, x1.w)};
        *(uint4*)&As[bs][row * 32 + lcol] = *(const uint4*)t;
      }
      gload_lds16(W + (size_t)(f0 + row) * 512 + kk + lcol, &Bs[bs][row * 32 + lcol]);
    }
  };

  stage(0, 0);
  for (int kk = 0; kk < 512; kk += 32) {
    const int cur = (kk >> 5) & 1;
    __syncthreads();                 // drains vmcnt: stage(cur) complete
    if (kk + 32 < 512) stage(cur ^ 1, kk + 32);  // prefetch next, hidden under MFMA
    short8 af[4], bf[4];
#pragma unroll
    for (int t = 0; t < 4; ++t)
      af[t] = *(const short8*)&As[cur][(wm + t * 16 + l15) * 32 + quad * 8];
#pragma unroll
    for (int t = 0; t < 4; ++t)
      bf[t] = *(const short8*)&Bs[cur][(wn + t * 16 + l15) * 32 + quad * 8];
#pragma unroll
    for (int mt = 0; mt < 4; ++mt)
#pragma unroll
      for (int nt = 0; nt < 4; ++nt)
        acc[mt][nt] = MFMA16(af[mt], bf[nt], acc[mt][nt]);
  }
  const float oscale = (seg == 0) ? C1 : 1.0f;
#pragma unroll
  for (int mt = 0; mt < 4; ++mt)
#pragma unroll
    for (int nt = 0; nt < 4; ++nt)
#pragma unroll
      for (int r = 0; r < 4; ++r) {
        int m  = m0 + wm + mt * 16 + quad * 4 + r;
        int nn = f0 + wn + nt * 16 + l15;
        int b = m >> 11, qq = m & 2047;
        int h = nn >> 6, hd = nn & 63;
        dst[(((size_t)(b * Hh + h)) * Qlen + qq) * HDim + hd] =
            f2h(acc[mt][nt][r] * oscale);
      }
}

// ============================================================
// V transpose (cnt != nullptr: skip tiles beyond padded key count)
// ============================================================
__global__ __launch_bounds__(256) void transpose_v(
    const unsigned short* __restrict__ Vp, unsigned short* __restrict__ Vt,
    const int* __restrict__ cnt) {
  __shared__ unsigned short t[64 * 72];
  const int bh = blockIdx.y, jt = blockIdx.x;
  if (cnt) {
    if (jt * 64 >= ((cnt[bh >> 3] + 63) & ~63)) return;
  }
  const int tid = threadIdx.x;
#pragma unroll
  for (int i = 0; i < 2; ++i) {
    int g = i * 256 + tid;
    int j = g >> 3, c8 = g & 7;
    *(uint4*)&t[j * 72 + c8 * 8] =
        *(const uint4*)(Vp + ((size_t)bh * Klen + jt * 64 + j) * 64 + c8 * 8);
  }
  __syncthreads();
#pragma unroll
  for (int i = 0; i < 2; ++i) {
    int g = i * 256 + tid;
    int d = g >> 3, j8 = g & 7;
    unsigned short tmp[8];
#pragma unroll
    for (int kx = 0; kx < 8; ++kx) tmp[kx] = t[(j8 * 8 + kx) * 72 + d];
    *(uint4*)(Vt + ((size_t)bh * HDim + d) * Klen + jt * 64 + j8 * 8) = *(const uint4*)tmp;
  }
}

// ============================================================
// Output projection, double-buffered staging (1 barrier/iter)
// ============================================================
__global__ __launch_bounds__(256) void gemm_out(
    const unsigned short* __restrict__ Oa,
    const unsigned short* __restrict__ Woh,
    float* __restrict__ out) {
  __shared__ unsigned short As[2][128 * 32];
  __shared__ unsigned short Bs[2][128 * 32];
  const int tid = threadIdx.x;
  const int w = tid >> 6, l = tid & 63;
  const int quad = l >> 4, l15 = l & 15;
  const int m0 = blockIdx.x * 128;
  const int n0 = blockIdx.y * 128;

  f32x4 acc[4][4] = {};
  const int lrow = l >> 2;
  const int lcol = (l & 3) * 8;
  const int wm = (w >> 1) * 64, wn = (w & 1) * 64;

  auto stage = [&](int bs, int kk) {
#pragma unroll
    for (int i = 0; i < 2; ++i) {
      int row = w * 32 + i * 16 + lrow;
      gload_lds16(Oa + (size_t)(m0 + row) * 512 + kk + lcol, &As[bs][row * 32 + lcol]);
      gload_lds16(Woh + (size_t)(n0 + row) * 512 + kk + lcol, &Bs[bs][row * 32 + lcol]);
    }
  };

  stage(0, 0);
  for (int kk = 0; kk < 512; kk += 32) {
    const int cur = (kk >> 5) & 1;
    __syncthreads();
    if (kk + 32 < 512) stage(cur ^ 1, kk + 32);
    short8 af[4], bf[4];
#pragma unroll
    for (int t = 0; t < 4; ++t)
      af[t] = *(const short8*)&As[cur][(wm + t * 16 + l15) * 32 + quad * 8];
#pragma unroll
    for (int t = 0; t < 4; ++t)
      bf[t] = *(const short8*)&Bs[cur][(wn + t * 16 + l15) * 32 + quad * 8];
#pragma unroll
    for (int mt = 0; mt < 4; ++mt)
#pragma unroll
      for (int nt = 0; nt < 4; ++nt)
        acc[mt][nt] = MFMA16(af[mt], bf[nt], acc[mt][nt]);
  }
#pragma unroll
  for (int mt = 0; mt < 4; ++mt)
#pragma unroll
    for (int nt = 0; nt < 4; ++nt)
#pragma unroll
      for (int r = 0; r < 4; ++r) {
        int m  = m0 + wm + mt * 16 + quad * 4 + r;
        int nn = n0 + wn + nt * 16 + l15;
        out[(size_t)m * 512 + nn] = acc[mt][nt][r];
      }
}

// ============================================================
// Flash attention — verified R8 per-wave body, widened to 8 waves
// per block (512 threads): each block owns a 128-row Q-tile, so one
// staged K/V tile feeds 2x the MFMA+VALU work (half the barriers and
// half the staging traffic per unit work). Grid 512 = 2 blocks/CU
// (16 waves/CU, same as R8). Per-wave code unchanged.
// ============================================================
template <bool KSPLIT, bool COMPACT>
__global__ __launch_bounds__(512, 4) void attn(
    const unsigned short* __restrict__ Qp,
    const unsigned short* __restrict__ Kp,
    const unsigned short* __restrict__ Vt,
    const float* __restrict__ biasf,
    const int* __restrict__ cntArr,
    unsigned short* __restrict__ Oa,     // !KSPLIT: (B,Q,D) out
    unsigned short* __restrict__ Op,     // KSPLIT: partial O (unused here)
    float* __restrict__ Sp) {            // KSPLIT: logsumexp (unused here)
  __shared__ unsigned short Ks[64 * 64];
  __shared__ unsigned short Vs[64 * 64];
  __shared__ unsigned short Ps[8][16 * 72];

  const int tid = threadIdx.x;
  const int w = tid >> 6, l = tid & 63;
  const int quad = l >> 4, l15 = l & 15;
  const int bid = blockIdx.x;
  const int bh = bid & 31;            // same bh -> same XCD
  const int b = bh >> 3, h = bh & 7;

  int cnt, KT;
  if constexpr (COMPACT) {
    cnt = cntArr[b];
    KT = (cnt + 63) >> 6;
  } else {
    cnt = Klen;
    KT = Klen / 64;
  }

  const int qt = bid >> 5;            // 128-row Q-tile index (0..15)
  const int kt0 = 0, ktN = KT;
  const int x = l15 & 7;
  const int qrow = qt * 128 + w * 16 + l15;

  short8 aq[2];
#pragma unroll
  for (int k2 = 0; k2 < 2; ++k2)
    aq[k2] = *(const short8*)(Qp + ((size_t)bh * Qlen + qrow) * HDim + (k2 * 4 + quad) * 8);

  short8 ones;
#pragma unroll
  for (int j = 0; j < 8; ++j) ones[j] = (short)0x3C00;  // fp16 1.0

  f32x4 o[4] = {};
  f32x4 o5 = {};                       // row-sum accumulator (l), via MFMA
  float m_run = -1.0e6f;
  const float* brow = biasf + b * Klen;  // only used when !COMPACT

  for (int kt = kt0; kt < ktN; ++kt) {
    __syncthreads();
    {
      int g = tid;                     // 512 threads cover the 8KB tile
      int row = g >> 3, c8 = g & 7;
      int sb = (c8 ^ (row & 7)) * 8;
      gload_lds16(Kp + ((size_t)bh * Klen + kt * 64 + row) * HDim + sb, &Ks[g * 8]);
      gload_lds16(Vt + ((size_t)bh * HDim + row) * Klen + kt * 64 + sb, &Vs[g * 8]);
    }
    float4 bb[4];
    if constexpr (!COMPACT) {
#pragma unroll
      for (int ct = 0; ct < 4; ++ct)
        bb[ct] = *(const float4*)(brow + kt * 64 + ct * 16 + quad * 4);
    }
    __syncthreads();

    // ---- S^T = K . Q^T (Q pre-scaled by C1 -> exp2 domain) ----
    f32x4 sv[4];
    __builtin_amdgcn_s_setprio(1);
#pragma unroll
    for (int ct = 0; ct < 4; ++ct) {
      const short8 bk0 = *(const short8*)&Ks[(ct * 16 + l15) * 64 + (quad ^ x) * 8];
      const short8 bk1 = *(const short8*)&Ks[(ct * 16 + l15) * 64 + ((4 + quad) ^ x) * 8];
      f32x4 a = {};
      a = MFMA16(bk0, aq[0], a);
      a = MFMA16(bk1, aq[1], a);
      sv[ct] = a;
    }
    __builtin_amdgcn_s_setprio(0);

    if constexpr (!COMPACT) {
#pragma unroll
      for (int ct = 0; ct < 4; ++ct)
#pragma unroll
        for (int r = 0; r < 4; ++r)
          sv[ct][r] += bb[ct][r];
    } else {
      if (kt == KT - 1) {  // mask the pad keys in the final tile
#pragma unroll
        for (int ct = 0; ct < 4; ++ct)
#pragma unroll
          for (int r = 0; r < 4; ++r)
            if (kt * 64 + ct * 16 + quad * 4 + r >= cnt) sv[ct][r] = -60000.0f;
      }
    }

    // ---- per-q max (cross-quad) + deferred rescale ----
    float mx0 = fmaxf(fmaxf(sv[0][0], sv[0][1]), fmaxf(sv[0][2], sv[0][3]));
    float mx1 = fmaxf(fmaxf(sv[1][0], sv[1][1]), fmaxf(sv[1][2], sv[1][3]));
    float mx2 = fmaxf(fmaxf(sv[2][0], sv[2][1]), fmaxf(sv[2][2], sv[2][3]));
    float mx3 = fmaxf(fmaxf(sv[3][0], sv[3][1]), fmaxf(sv[3][2], sv[3][3]));
    float mx = fmaxf(fmaxf(mx0, mx1), fmaxf(mx2, mx3));
    mx = fmaxf(mx, __shfl_xor(mx, 16));
    mx = fmaxf(mx, __shfl_xor(mx, 32));
    if (__any(mx > m_run + 8.0f)) {
      float mnew  = fmaxf(m_run, mx);
      float alpha = exp2f(m_run - mnew);
      m_run = mnew;
#pragma unroll
      for (int ctd = 0; ctd < 4; ++ctd) o[ctd] *= alpha;
      o5 *= alpha;
    }

    // ---- P = exp2(S - m), pack to wave-private Ps ----
#pragma unroll
    for (int ct = 0; ct < 4; ++ct) {
      float p0 = exp2f(sv[ct][0] - m_run);
      float p1 = exp2f(sv[ct][1] - m_run);
      float p2 = exp2f(sv[ct][2] - m_run);
      float p3 = exp2f(sv[ct][3] - m_run);
      unsigned pk[2] = {pk2h(p0, p1), pk2h(p2, p3)};
      *(uint2*)&Ps[w][l15 * 72 + ct * 16 + quad * 4] = *(const uint2*)pk;
    }
    const short8 ap0 = *(const short8*)&Ps[w][l15 * 72 + quad * 8];
    const short8 ap1 = *(const short8*)&Ps[w][l15 * 72 + 32 + quad * 8];

    // ---- l += ones . P^T ; O^T += V^T . P^T ----
    __builtin_amdgcn_s_setprio(1);
    o5 = MFMA16(ones, ap0, o5);
    o5 = MFMA16(ones, ap1, o5);
#pragma unroll
    for (int ctd = 0; ctd < 4; ++ctd) {
      const short8 bv0 = *(const short8*)&Vs[(ctd * 16 + l15) * 64 + (quad ^ x) * 8];
      const short8 bv1 = *(const short8*)&Vs[(ctd * 16 + l15) * 64 + ((4 + quad) ^ x) * 8];
      o[ctd] = MFMA16(bv0, ap0, o[ctd]);
      o[ctd] = MFMA16(bv1, ap1, o[ctd]);
    }
    __builtin_amdgcn_s_setprio(0);
  }

  // ---- epilogue: l is replicated in every element of o5 ----
  float lt = o5[0];
  float rl = (lt > 0.0f) ? 1.0f / lt : 0.0f;
  const size_t obase = ((size_t)(b * Qlen) + qrow) * Dm + h * 64;
#pragma unroll
  for (int ctd = 0; ctd < 4; ++ctd) {
    unsigned pk[2] = {pk2h(o[ctd][0] * rl, o[ctd][1] * rl),
                      pk2h(o[ctd][2] * rl, o[ctd][3] * rl)};
    *(uint2*)(Oa + obase + ctd * 16 + quad * 4) = *(const uint2*)pk;
  }
}

extern "C" void kernel_launch(void* const* d_in, const int* in_sizes, int n_in,
                              void* d_out, int out_size, void* d_ws, size_t ws_size,
                              hipStream_t stream) {
  const float* q  = (const float*)d_in[0];
  const float* k  = (const float*)d_in[1];
  const float* v  = (const float*)d_in[2];
  const float* Wq = (const float*)d_in[3];
  const float* Wk = (const float*)d_in[4];
  const float* Wv = (const float*)d_in[5];
  const float* Wo = (const float*)d_in[6];
  const int*  msk = (const int*)d_in[7];
  float* out = (float*)d_out;

  char* ws = (char*)d_ws;
  const size_t SEG  = (size_t)Bc * Hh * Qlen * HDim * sizeof(unsigned short); // 8 MB
  const size_t WSEG = (size_t)Dm * Dm * sizeof(unsigned short);               // 0.5 MB
  unsigned short* Qp  = (unsigned short*)(ws);
  unsigned short* Kp  = (unsigned short*)(ws + SEG);
  unsigned short* Vp  = (unsigned short*)(ws + 2 * SEG);
  unsigned short* Vt  = (unsigned short*)(ws + 3 * SEG);
  unsigned short* Oa  = Vp;  // Vp dead after transpose_v; attn writes (B,Q,D) here
  unsigned short* Wqh = (unsigned short*)(ws + 4 * SEG);
  unsigned short* Wkh = (unsigned short*)(ws + 4 * SEG + WSEG);
  unsigned short* Wvh = (unsigned short*)(ws + 4 * SEG + 2 * WSEG);
  unsigned short* Woh = (unsigned short*)(ws + 4 * SEG + 3 * WSEG);
  // 64 KB region: big path = idx (32 KB) + cnt; small path = f32 bias (32 KB)
  int*   idxArr = (int*)(ws + 4 * SEG + 4 * WSEG);
  int*   cntArr = idxArr + Bc * Klen;
  float* Bfs    = (float*)idxArr;
  unsigned short* qh  = (unsigned short*)(ws + 4 * SEG + 4 * WSEG + 65536);
  unsigned short* kh  = qh + SEG / 2;
  unsigned short* vh  = kh + SEG / 2;
  const size_t NEED = 4 * SEG + 4 * WSEG + 65536 + 3 * SEG;
  const bool big = ws_size >= NEED;

  // bind multi-arg template instantiations outside the launch macro
  auto attn_one    = attn<false, true>;
  auto attn_single = attn<false, false>;

  const int wn = Dm * Dm;
  if (big) {
    hipLaunchKernelGGL(scan_mask, dim3(Bc), dim3(256), 0, stream, msk, idxArr, cntArr);
    hipLaunchKernelGGL(cvt4, dim3(wn / 1024, 4), dim3(256), 0, stream,
                       Wq, Wk, Wv, Wo, Wqh, Wkh, Wvh, Woh, msk, Bfs);
    hipLaunchKernelGGL(cvt_in, dim3(4096, 3), dim3(256), 0, stream,
                       q, k, v, qh, kh, vh, idxArr, cntArr);
    hipLaunchKernelGGL(gemm_qkv<true>, dim3(64, 12), dim3(256), 0, stream,
                       q, k, v, qh, kh, vh, Wqh, Wkh, Wvh, Qp, Kp, Vp, cntArr);
    hipLaunchKernelGGL(transpose_v, dim3(32, 32), dim3(256), 0, stream, Vp, Vt, cntArr);
    hipLaunchKernelGGL(attn_one, dim3(512), dim3(512), 0, stream,
                       Qp, Kp, Vt, Bfs, cntArr, Oa,
                       (unsigned short*)nullptr, (float*)nullptr);
  } else {
    hipLaunchKernelGGL(cvt4, dim3(wn / 1024, 5), dim3(256), 0, stream,
                       Wq, Wk, Wv, Wo, Wqh, Wkh, Wvh, Woh, msk, Bfs);
    hipLaunchKernelGGL(gemm_qkv<false>, dim3(64, 12), dim3(256), 0, stream,
                       q, k, v, qh, kh, vh, Wqh, Wkh, Wvh, Qp, Kp, Vp, cntArr);
    hipLaunchKernelGGL(transpose_v, dim3(32, 32), dim3(256), 0, stream, Vp, Vt,
                       (const int*)nullptr);
    hipLaunchKernelGGL(attn_single, dim3(512), dim3(512), 0, stream,
                       Qp, Kp, Vt, Bfs, (const int*)nullptr, Oa,
                       (unsigned short*)nullptr, (float*)nullptr);
  }
  hipLaunchKernelGGL(gemm_out, dim3(64, 4), dim3(256), 0, stream, Oa, Woh, out);
}